// Round 9
// baseline (197.310 us; speedup 1.0000x reference)
//
#include <hip/hip_runtime.h>

#define N_NODES 50000
#define N_EDGES 800000

#define NBUCK   1024                 // bucket id = dst >> 6 (<= 781 used)
#define BNODES  64
#define NB_USED 782                  // ceil(50000/64)
#define CAP     2560                 // raw slots per bucket (mean 1024, sigma 32)
#define CAP2    3072                 // padded slots per bucket (CAP + 64*8)
#define ZROW    50000                // dummy zero row index (ushort-safe)
#define SC_BLK  1024
#define SC_EPT  4
#define SC_EPB  (SC_BLK * SC_EPT)    // 4096
#define SC_NBLK ((N_EDGES + SC_EPB - 1) / SC_EPB)   // 196

typedef unsigned short ushort_t;

static __device__ __forceinline__ ushort_t f2bf(float x) {
    unsigned b = __float_as_uint(x);
    unsigned r = (b + 0x7FFFu + ((b >> 16) & 1u)) >> 16;   // RNE
    return (ushort_t)r;
}
static __device__ __forceinline__ float bf2f(ushort_t u) {
    return __uint_as_float(((unsigned)u) << 16);
}

// ---------------------------------------------------------------------------
// Direct bucket scatter into fixed-capacity bucket slabs. Per block: LDS
// bucket-sort of 4096 edges, ONE global atomic per (block,bucket) reserves a
// run in ebuf[bucket*CAP ...], then coalesced burst writes.
// Edge packed as (dst<<16)|src (both < 65536). Scan via shfl (3 barriers).
// ---------------------------------------------------------------------------
__global__ __launch_bounds__(SC_BLK) void scatter_direct(const int* __restrict__ src,
                                                         const int* __restrict__ dst,
                                                         int* __restrict__ cursor,
                                                         unsigned* __restrict__ ebuf) {
    __shared__ int h[NBUCK];
    __shared__ int hs[NBUCK];
    __shared__ int gbase[NBUCK];
    __shared__ int wsum[16];
    __shared__ unsigned stage[SC_EPB];
    int t = threadIdx.x;
    int lane = t & 63, wid = t >> 6;
    h[t] = 0;
    __syncthreads();

    long long base = (long long)blockIdx.x * SC_EPB;
    unsigned pk[SC_EPT];
    int rk[SC_EPT];
    int nv = 0;
#pragma unroll
    for (int j = 0; j < SC_EPT; ++j) {
        long long e = base + (long long)j * SC_BLK + t;
        if (e < N_EDGES) {
            int d = dst[e], s = src[e];
            pk[j] = ((unsigned)d << 16) | (unsigned)s;
            rk[j] = atomicAdd(&h[d >> 6], 1);
            nv = j + 1;
        }
    }
    __syncthreads();

    int cnt = h[t];
    // wave-level inclusive shfl scan of cnt (64 lanes)
    int pr = cnt;
#pragma unroll
    for (int off = 1; off < 64; off <<= 1) {
        int u = __shfl_up(pr, off, 64);
        if (lane >= off) pr += u;
    }
    if (lane == 63) wsum[wid] = pr;
    __syncthreads();
    if (t < 16) {                     // exclusive scan of the 16 wave totals
        int v = wsum[t], p2 = v;
#pragma unroll
        for (int off = 1; off < 16; off <<= 1) {
            int u = __shfl_up(p2, off, 16);
            if (t >= off) p2 += u;
        }
        wsum[t] = p2 - v;
    }
    __syncthreads();
    hs[t] = pr - cnt + wsum[wid];     // block-local exclusive start
    if (cnt) gbase[t] = atomicAdd(&cursor[t], cnt);
    __syncthreads();

#pragma unroll
    for (int j = 0; j < SC_EPT; ++j) {
        if (j < nv) {
            int b = pk[j] >> 22;
            stage[hs[b] + rk[j]] = pk[j];
        }
    }
    __syncthreads();

    int total = (int)((N_EDGES - base < SC_EPB) ? (N_EDGES - base) : SC_EPB);
    for (int i = t; i < total; i += SC_BLK) {
        unsigned p = stage[i];
        int b = p >> 22;
        int idx = gbase[b] + (i - hs[b]);
        if (idx < CAP) ebuf[(size_t)b * CAP + idx] = p;   // overflow-safe guard
    }
}

// ---------------------------------------------------------------------------
// Per-bucket refine: counting-sort edges by local node id, runs PADDED to a
// multiple of 8 with dummy src=ZROW (zero row). Emits ushort src list esrc,
// padded run table nstart[b*65+0..64], and REAL degrees ndeg[b*64+..].
// ---------------------------------------------------------------------------
__global__ __launch_bounds__(256) void refine_sort(const int* __restrict__ cursor,
                                                   const unsigned* __restrict__ ebuf,
                                                   ushort_t* __restrict__ esrc,
                                                   int* __restrict__ nstart,
                                                   int* __restrict__ ndeg) {
    __shared__ int bins[BNODES];
    __shared__ int bcur[BNODES];
    __shared__ int tot;
    __shared__ unsigned estage[CAP];
    __shared__ ushort_t esortS[CAP2];
    int t = threadIdx.x, b = blockIdx.x;

    int n = cursor[b];
    if (n > CAP) n = CAP;
    if (t < BNODES) bins[t] = 0;
    __syncthreads();

    for (int i = t; i < n; i += 256) {
        unsigned p = ebuf[(size_t)b * CAP + i];
        estage[i] = p;
        atomicAdd(&bins[(p >> 16) & 63], 1);
    }
    __syncthreads();

    if (t < 64) {                              // wave-0 shfl scan of padded bins
        int real = bins[t];
        int pad8 = (real + 7) & ~7;
        int pr = pad8;
#pragma unroll
        for (int off = 1; off < 64; off <<= 1) {
            int u = __shfl_up(pr, off, 64);
            if (t >= off) pr += u;
        }
        int excl = pr - pad8;
        bcur[t] = excl;
        nstart[b * 65 + t] = excl;
        ndeg[b * 64 + t] = real;
        if (t == 63) { nstart[b * 65 + 64] = pr; tot = pr; }
    }
    __syncthreads();

    for (int i = t; i < n; i += 256) {
        unsigned p = estage[i];
        esortS[atomicAdd(&bcur[(p >> 16) & 63], 1)] = (ushort_t)p;
    }
    __syncthreads();

    if (t < 64) {                              // pad fill (<8 entries per node)
        int e8 = nstart[b * 65 + t + 1];
        for (int q = bcur[t]; q < e8; ++q) esortS[q] = (ushort_t)ZROW;
    }
    __syncthreads();

    int nt = tot;
    for (int i = t; i < nt; i += 256)
        esrc[(size_t)b * CAP2 + i] = esortS[i];  // coalesced ushort burst
}

// ---------------------------------------------------------------------------
// Dual linear (layer 1): Yb = bf16(X @ Wl^T), Z = X @ Wr^T. K=64, OUTF=64.
// ---------------------------------------------------------------------------
__global__ __launch_bounds__(256) void mm_dual64(const float* __restrict__ X,
                                                 const float* __restrict__ Wl,
                                                 const float* __restrict__ Wr,
                                                 ushort_t* __restrict__ Yb,
                                                 float* __restrict__ Z) {
    constexpr int K = 64, OUTF = 64, NPB = 4, PAD = 68;
    __shared__ float wl_s[OUTF * PAD];
    __shared__ float wr_s[OUTF * PAD];
    __shared__ float x_s[NPB * PAD];
    int t = threadIdx.x;

    for (int i = t; i < OUTF * (K / 4); i += 256) {
        int o = i >> 4, k4 = i & 15;
        *reinterpret_cast<float4*>(&wl_s[o * PAD + k4 * 4]) =
            reinterpret_cast<const float4*>(Wl)[i];
        *reinterpret_cast<float4*>(&wr_s[o * PAD + k4 * 4]) =
            reinterpret_cast<const float4*>(Wr)[i];
    }
    int base = blockIdx.x * NPB;
    for (int i = t; i < NPB * (K / 4); i += 256) {
        int nl = i >> 4, k4 = i & 15;
        *reinterpret_cast<float4*>(&x_s[nl * PAD + k4 * 4]) =
            reinterpret_cast<const float4*>(X)[(size_t)base * (K / 4) + i];
    }
    __syncthreads();

    int nl = t / OUTF, o = t % OUTF;
    const float4* xv = reinterpret_cast<const float4*>(&x_s[nl * PAD]);
    const float4* lv = reinterpret_cast<const float4*>(&wl_s[o * PAD]);
    const float4* rv = reinterpret_cast<const float4*>(&wr_s[o * PAD]);
    float4 aY = {0.f, 0.f, 0.f, 0.f}, aZ = {0.f, 0.f, 0.f, 0.f};
#pragma unroll
    for (int kk = 0; kk < K / 4; ++kk) {
        float4 x4 = xv[kk], l4 = lv[kk], r4 = rv[kk];
        aY.x += x4.x * l4.x; aY.y += x4.y * l4.y;
        aY.z += x4.z * l4.z; aY.w += x4.w * l4.w;
        aZ.x += x4.x * r4.x; aZ.y += x4.y * r4.y;
        aZ.z += x4.z * r4.z; aZ.w += x4.w * r4.w;
    }
    int n = base + nl;
    Yb[(size_t)n * OUTF + o] = f2bf((aY.x + aY.y) + (aY.z + aY.w));
    Z[(size_t)n * OUTF + o] = (aZ.x + aZ.y) + (aZ.z + aZ.w);
}

// ---------------------------------------------------------------------------
// Layer-1 aggregate: HALF-bucket per block (32 nodes), branchless step-8
// gather of padded runs, finalize h in LDS, fused 32-wide dual mm.
// Wave w owns nodes {w+8k}, k<4. sub=lane>>5 (edge parity), fp=lane&31 ->
// feats {2fp,2fp+1}. LDS ~31KB -> 4 blocks/CU (thread-capped).
// ---------------------------------------------------------------------------
__global__ __launch_bounds__(512) void agg_layer1(const ushort_t* __restrict__ y1b,
                                                  const float* __restrict__ z1,
                                                  const float* __restrict__ bl1,
                                                  const float* __restrict__ Wl2,
                                                  const float* __restrict__ Wr2,
                                                  const int* __restrict__ nstart,
                                                  const int* __restrict__ ndeg,
                                                  const ushort_t* __restrict__ esrc,
                                                  ushort_t* __restrict__ y2b,
                                                  float* __restrict__ z2) {
    __shared__ ushort_t esrcS[CAP2];      //  6.1 KB
    __shared__ float hld[32 * 66];        //  8.4 KB
    __shared__ float wcat[64 * 65];       // 16.6 KB  [Wl2 | Wr2]
    __shared__ float bls[64];

    int t = threadIdx.x;
    int bkt = blockIdx.x >> 1, half = blockIdx.x & 1;
    int lane = t & 63, w = t >> 6;
    int sub = lane >> 5, fp = lane & 31;

    for (int i = t; i < 32 * 64; i += 512) {
        int o = i >> 6, f = i & 63;
        wcat[o * 65 + f] = Wl2[i];
        wcat[(o + 32) * 65 + f] = Wr2[i];
    }
    if (t < 64) bls[t] = bl1[t];

    const int nb = bkt * 65;
    int sbeg = nstart[nb + 32 * half];
    int send = nstart[nb + 32 * half + 32];
    for (int i = sbeg + t; i < send; i += 512)
        esrcS[i - sbeg] = esrc[(size_t)bkt * CAP2 + i];
    __syncthreads();

    float acc0[4], acc1[4], deg[4];
#pragma unroll
    for (int k = 0; k < 4; ++k) {
        int nl = w + 8 * k;                       // 0..31 (local)
        int rb = nstart[nb + 32 * half + nl] - sbeg;
        int re = nstart[nb + 32 * half + nl + 1] - sbeg;
        deg[k] = (float)ndeg[bkt * 64 + 32 * half + nl];
        float a0 = 0.f, a1 = 0.f;
        for (int j = rb; j < re; j += 8) {        // branchless: runs are x8
            unsigned sA = esrcS[j + sub],     sB = esrcS[j + 2 + sub];
            unsigned sC = esrcS[j + 4 + sub], sD = esrcS[j + 6 + sub];
            unsigned a = *reinterpret_cast<const unsigned*>(&y1b[(size_t)sA * 64 + 2 * fp]);
            unsigned bb = *reinterpret_cast<const unsigned*>(&y1b[(size_t)sB * 64 + 2 * fp]);
            unsigned c = *reinterpret_cast<const unsigned*>(&y1b[(size_t)sC * 64 + 2 * fp]);
            unsigned d = *reinterpret_cast<const unsigned*>(&y1b[(size_t)sD * 64 + 2 * fp]);
            a0 += bf2f((ushort_t)(a & 0xFFFF)) + bf2f((ushort_t)(bb & 0xFFFF))
                + bf2f((ushort_t)(c & 0xFFFF)) + bf2f((ushort_t)(d & 0xFFFF));
            a1 += bf2f((ushort_t)(a >> 16)) + bf2f((ushort_t)(bb >> 16))
                + bf2f((ushort_t)(c >> 16)) + bf2f((ushort_t)(d >> 16));
        }
        acc0[k] = a0;
        acc1[k] = a1;
    }

    // finalize h = relu(acc/deg + bl1 + z1) into LDS
    int nodeBase = bkt * BNODES + 32 * half;
#pragma unroll
    for (int k = 0; k < 4; ++k) {
        int nl = w + 8 * k;
        float s0 = acc0[k] + __shfl_xor(acc0[k], 32, 64);
        float s1 = acc1[k] + __shfl_xor(acc1[k], 32, 64);
        int gn = nodeBase + nl;
        if (sub == 0 && gn < N_NODES) {
            float inv = 1.f / fmaxf(deg[k], 1.f);
            float2 zv = *reinterpret_cast<const float2*>(&z1[(size_t)gn * 64 + 2 * fp]);
            float h0 = fmaxf(s0 * inv + bls[2 * fp] + zv.x, 0.f);
            float h1 = fmaxf(s1 * inv + bls[2 * fp + 1] + zv.y, 0.f);
            *reinterpret_cast<float2*>(&hld[nl * 66 + 2 * fp]) = make_float2(h0, h1);
        }
    }
    __syncthreads();

    // fused dual mm: lane l -> concat output l (l<32: y2 bf16, else z2 f32)
#pragma unroll
    for (int kp = 0; kp < 2; ++kp) {
        int nlA = w + 16 * kp, nlB = nlA + 8;
        float sA = 0.f, sB = 0.f;
        const float* wrow = &wcat[lane * 65];
#pragma unroll 8
        for (int f = 0; f < 64; ++f) {
            float wv = wrow[f];
            sA += hld[nlA * 66 + f] * wv;
            sB += hld[nlB * 66 + f] * wv;
        }
        int gA = nodeBase + nlA, gB = nodeBase + nlB;
        int o = lane & 31;
        if (gA < N_NODES) {
            if (lane < 32) y2b[(size_t)gA * 32 + o] = f2bf(sA);
            else           z2[(size_t)gA * 32 + o] = sA;
        }
        if (gB < N_NODES) {
            if (lane < 32) y2b[(size_t)gB * 32 + o] = f2bf(sB);
            else           z2[(size_t)gB * 32 + o] = sB;
        }
    }
}

// ---------------------------------------------------------------------------
// Layer-2 aggregate: HALF-bucket per block, padded runs (x8), step-16 main
// loop (4 loads in flight) + one 8-step. sub4=lane>>4, fp=lane&15.
// out = mean + bl2 + z2.
// ---------------------------------------------------------------------------
__global__ __launch_bounds__(512) void agg_layer2(const ushort_t* __restrict__ y2b,
                                                  const float* __restrict__ z2,
                                                  const float* __restrict__ bl2,
                                                  const int* __restrict__ nstart,
                                                  const int* __restrict__ ndeg,
                                                  const ushort_t* __restrict__ esrc,
                                                  float* __restrict__ out) {
    __shared__ ushort_t esrcS[CAP2];
    __shared__ float bls[32];
    int t = threadIdx.x;
    int bkt = blockIdx.x >> 1, half = blockIdx.x & 1;
    int lane = t & 63, w = t >> 6;
    int sub4 = lane >> 4, fp = lane & 15;

    if (t < 32) bls[t] = bl2[t];
    const int nb = bkt * 65;
    int sbeg = nstart[nb + 32 * half];
    int send = nstart[nb + 32 * half + 32];
    for (int i = sbeg + t; i < send; i += 512)
        esrcS[i - sbeg] = esrc[(size_t)bkt * CAP2 + i];
    __syncthreads();

    int nodeBase = bkt * BNODES + 32 * half;
#pragma unroll
    for (int k = 0; k < 4; ++k) {
        int nl = w + 8 * k;
        int rb = nstart[nb + 32 * half + nl] - sbeg;
        int re = nstart[nb + 32 * half + nl + 1] - sbeg;
        float a0 = 0.f, a1 = 0.f;
        int j = rb;
        for (; j + 15 < re; j += 16) {            // 4 loads in flight
            unsigned sA = esrcS[j + sub4],      sB = esrcS[j + 4 + sub4];
            unsigned sC = esrcS[j + 8 + sub4],  sD = esrcS[j + 12 + sub4];
            unsigned a = *reinterpret_cast<const unsigned*>(&y2b[(size_t)sA * 32 + 2 * fp]);
            unsigned bb = *reinterpret_cast<const unsigned*>(&y2b[(size_t)sB * 32 + 2 * fp]);
            unsigned c = *reinterpret_cast<const unsigned*>(&y2b[(size_t)sC * 32 + 2 * fp]);
            unsigned d = *reinterpret_cast<const unsigned*>(&y2b[(size_t)sD * 32 + 2 * fp]);
            a0 += bf2f((ushort_t)(a & 0xFFFF)) + bf2f((ushort_t)(bb & 0xFFFF))
                + bf2f((ushort_t)(c & 0xFFFF)) + bf2f((ushort_t)(d & 0xFFFF));
            a1 += bf2f((ushort_t)(a >> 16)) + bf2f((ushort_t)(bb >> 16))
                + bf2f((ushort_t)(c >> 16)) + bf2f((ushort_t)(d >> 16));
        }
        if (j < re) {                             // exactly one 8-step remains
            unsigned sA = esrcS[j + sub4], sB = esrcS[j + 4 + sub4];
            unsigned a = *reinterpret_cast<const unsigned*>(&y2b[(size_t)sA * 32 + 2 * fp]);
            unsigned bb = *reinterpret_cast<const unsigned*>(&y2b[(size_t)sB * 32 + 2 * fp]);
            a0 += bf2f((ushort_t)(a & 0xFFFF)) + bf2f((ushort_t)(bb & 0xFFFF));
            a1 += bf2f((ushort_t)(a >> 16)) + bf2f((ushort_t)(bb >> 16));
        }

        a0 += __shfl_xor(a0, 16, 64); a0 += __shfl_xor(a0, 32, 64);
        a1 += __shfl_xor(a1, 16, 64); a1 += __shfl_xor(a1, 32, 64);
        int gn = nodeBase + nl;
        if (sub4 == 0 && gn < N_NODES) {
            float inv = 1.f / fmaxf((float)ndeg[bkt * 64 + 32 * half + nl], 1.f);
            float2 zv = *reinterpret_cast<const float2*>(&z2[(size_t)gn * 32 + 2 * fp]);
            float2 ov;
            ov.x = a0 * inv + bls[2 * fp] + zv.x;
            ov.y = a1 * inv + bls[2 * fp + 1] + zv.y;
            *reinterpret_cast<float2*>(&out[(size_t)gn * 32 + 2 * fp]) = ov;
        }
    }
}

extern "C" void kernel_launch(void* const* d_in, const int* in_sizes, int n_in,
                              void* d_out, int out_size, void* d_ws, size_t ws_size,
                              hipStream_t stream) {
    const float* x   = (const float*)d_in[0];
    const int*   ei  = (const int*)d_in[1];   // (2, N_EDGES) int32
    const float* Wl1 = (const float*)d_in[2];
    const float* bl1 = (const float*)d_in[3];
    const float* Wr1 = (const float*)d_in[4];
    const float* Wl2 = (const float*)d_in[5];
    const float* bl2 = (const float*)d_in[6];
    const float* Wr2 = (const float*)d_in[7];
    float* out = (float*)d_out;

    const int* src = ei;
    const int* dst = ei + N_EDGES;

    // Workspace layout (byte offsets). Total ~42.0 MB. y1b/y2b have an extra
    // zero row at index 50000 (gather-padding target).
    char* wsb = (char*)d_ws;
    int*      cursor = (int*)(wsb + 0);              //  4 KB (zeroed)
    unsigned* ebuf   = (unsigned*)(wsb + 4096);      //  782*2560*4  = 8,007,680
    ushort_t* esrc   = (ushort_t*)(wsb + 8011776);   //  782*3072*2  = 4,804,608
    int*      nstart = (int*)(wsb + 12816384);       //  782*65*4    =   203,320
    int*      ndeg   = (int*)(wsb + 13019712);       //  782*64*4    =   200,192
    ushort_t* y1b    = (ushort_t*)(wsb + 13219904);  //  50001*64*2  = 6,400,128
    float*    z1     = (float*)(wsb + 19620032);     //  50000*64*4  = 12,800,000
    ushort_t* y2b    = (ushort_t*)(wsb + 32420032);  //  50001*32*2  = 3,200,064
    float*    z2     = (float*)(wsb + 35620096);     //  50000*32*4  = 6,400,000

    hipMemsetAsync(cursor, 0, NBUCK * sizeof(int), stream);
    hipMemsetAsync((char*)y1b + (size_t)ZROW * 64 * 2, 0, 128, stream);  // zero row
    hipMemsetAsync((char*)y2b + (size_t)ZROW * 32 * 2, 0, 64, stream);   // zero row

    scatter_direct<<<SC_NBLK, SC_BLK, 0, stream>>>(src, dst, cursor, ebuf);
    refine_sort<<<NB_USED, 256, 0, stream>>>(cursor, ebuf, esrc, nstart, ndeg);

    mm_dual64<<<N_NODES / 4, 256, 0, stream>>>(x, Wl1, Wr1, y1b, z1);
    agg_layer1<<<NB_USED * 2, 512, 0, stream>>>(y1b, z1, bl1, Wl2, Wr2, nstart, ndeg, esrc, y2b, z2);
    agg_layer2<<<NB_USED * 2, 512, 0, stream>>>(y2b, z2, bl2, nstart, ndeg, esrc, out);
}

// Round 10
// 185.567 us; speedup vs baseline: 1.0633x; 1.0633x over previous
//
#include <hip/hip_runtime.h>

#define N_NODES 50000
#define N_EDGES 800000

#define NBUCK   1024                 // bucket id = dst >> 6 (<= 781 used)
#define BNODES  64
#define NB_USED 782                  // ceil(50000/64)
#define CAP     2560                 // raw slots per bucket (mean 1024, sigma 32)
#define CAP2    3072                 // padded slots per bucket
#define ZROW    50000                // dummy zero row index (gather pad target)
#define SC_BLK  1024
#define SC_EPT  4
#define SC_EPB  (SC_BLK * SC_EPT)    // 4096
#define SC_NBLK ((N_EDGES + SC_EPB - 1) / SC_EPB)   // 196
#define MMG     10                   // node-groups per mm block (40 nodes/block)

typedef unsigned short ushort_t;

static __device__ __forceinline__ ushort_t f2bf(float x) {
    unsigned b = __float_as_uint(x);
    unsigned r = (b + 0x7FFFu + ((b >> 16) & 1u)) >> 16;   // RNE
    return (ushort_t)r;
}
static __device__ __forceinline__ float bf2f(ushort_t u) {
    return __uint_as_float(((unsigned)u) << 16);
}

// ---------------------------------------------------------------------------
// Direct bucket scatter into fixed-capacity bucket slabs (unchanged r9).
// ---------------------------------------------------------------------------
__global__ __launch_bounds__(SC_BLK) void scatter_direct(const int* __restrict__ src,
                                                         const int* __restrict__ dst,
                                                         int* __restrict__ cursor,
                                                         unsigned* __restrict__ ebuf) {
    __shared__ int h[NBUCK];
    __shared__ int hs[NBUCK];
    __shared__ int gbase[NBUCK];
    __shared__ int wsum[16];
    __shared__ unsigned stage[SC_EPB];
    int t = threadIdx.x;
    int lane = t & 63, wid = t >> 6;
    h[t] = 0;
    __syncthreads();

    long long base = (long long)blockIdx.x * SC_EPB;
    unsigned pk[SC_EPT];
    int rk[SC_EPT];
    int nv = 0;
#pragma unroll
    for (int j = 0; j < SC_EPT; ++j) {
        long long e = base + (long long)j * SC_BLK + t;
        if (e < N_EDGES) {
            int d = dst[e], s = src[e];
            pk[j] = ((unsigned)d << 16) | (unsigned)s;
            rk[j] = atomicAdd(&h[d >> 6], 1);
            nv = j + 1;
        }
    }
    __syncthreads();

    int cnt = h[t];
    int pr = cnt;
#pragma unroll
    for (int off = 1; off < 64; off <<= 1) {
        int u = __shfl_up(pr, off, 64);
        if (lane >= off) pr += u;
    }
    if (lane == 63) wsum[wid] = pr;
    __syncthreads();
    if (t < 16) {
        int v = wsum[t], p2 = v;
#pragma unroll
        for (int off = 1; off < 16; off <<= 1) {
            int u = __shfl_up(p2, off, 16);
            if (t >= off) p2 += u;
        }
        wsum[t] = p2 - v;
    }
    __syncthreads();
    hs[t] = pr - cnt + wsum[wid];
    if (cnt) gbase[t] = atomicAdd(&cursor[t], cnt);
    __syncthreads();

#pragma unroll
    for (int j = 0; j < SC_EPT; ++j) {
        if (j < nv) {
            int b = pk[j] >> 22;
            stage[hs[b] + rk[j]] = pk[j];
        }
    }
    __syncthreads();

    int total = (int)((N_EDGES - base < SC_EPB) ? (N_EDGES - base) : SC_EPB);
    for (int i = t; i < total; i += SC_BLK) {
        unsigned p = stage[i];
        int b = p >> 22;
        int idx = gbase[b] + (i - hs[b]);
        if (idx < CAP) ebuf[(size_t)b * CAP + idx] = p;
    }
}

// ---------------------------------------------------------------------------
// Per-bucket refine: counting-sort by local node id, runs padded to x8 with
// src=ZROW. Emits esrc, nstart (padded offsets), ndeg (real degrees).
// (unchanged r9)
// ---------------------------------------------------------------------------
__global__ __launch_bounds__(256) void refine_sort(const int* __restrict__ cursor,
                                                   const unsigned* __restrict__ ebuf,
                                                   ushort_t* __restrict__ esrc,
                                                   int* __restrict__ nstart,
                                                   int* __restrict__ ndeg) {
    __shared__ int bins[BNODES];
    __shared__ int bcur[BNODES];
    __shared__ int tot;
    __shared__ unsigned estage[CAP];
    __shared__ ushort_t esortS[CAP2];
    int t = threadIdx.x, b = blockIdx.x;

    int n = cursor[b];
    if (n > CAP) n = CAP;
    if (t < BNODES) bins[t] = 0;
    __syncthreads();

    for (int i = t; i < n; i += 256) {
        unsigned p = ebuf[(size_t)b * CAP + i];
        estage[i] = p;
        atomicAdd(&bins[(p >> 16) & 63], 1);
    }
    __syncthreads();

    if (t < 64) {
        int real = bins[t];
        int pad8 = (real + 7) & ~7;
        int pr = pad8;
#pragma unroll
        for (int off = 1; off < 64; off <<= 1) {
            int u = __shfl_up(pr, off, 64);
            if (t >= off) pr += u;
        }
        int excl = pr - pad8;
        bcur[t] = excl;
        nstart[b * 65 + t] = excl;
        ndeg[b * 64 + t] = real;
        if (t == 63) { nstart[b * 65 + 64] = pr; tot = pr; }
    }
    __syncthreads();

    for (int i = t; i < n; i += 256) {
        unsigned p = estage[i];
        esortS[atomicAdd(&bcur[(p >> 16) & 63], 1)] = (ushort_t)p;
    }
    __syncthreads();

    if (t < 64) {
        int e8 = nstart[b * 65 + t + 1];
        for (int q = bcur[t]; q < e8; ++q) esortS[q] = (ushort_t)ZROW;
    }
    __syncthreads();

    int nt = tot;
    for (int i = t; i < nt; i += 256)
        esrc[(size_t)b * CAP2 + i] = esortS[i];
}

// ---------------------------------------------------------------------------
// Dual linear (layer 1): Yb = bf16(X @ Wl^T), Zb = bf16(X @ Wr^T).
// Weights staged ONCE per block; MMG node-groups looped (40 nodes/block).
// ---------------------------------------------------------------------------
__global__ __launch_bounds__(256) void mm_dual64(const float* __restrict__ X,
                                                 const float* __restrict__ Wl,
                                                 const float* __restrict__ Wr,
                                                 ushort_t* __restrict__ Yb,
                                                 ushort_t* __restrict__ Zb) {
    constexpr int K = 64, OUTF = 64, NPB = 4, PAD = 68;
    __shared__ float wl_s[OUTF * PAD];
    __shared__ float wr_s[OUTF * PAD];
    __shared__ float x_s[NPB * PAD];
    int t = threadIdx.x;

    for (int i = t; i < OUTF * (K / 4); i += 256) {
        int o = i >> 4, k4 = i & 15;
        *reinterpret_cast<float4*>(&wl_s[o * PAD + k4 * 4]) =
            reinterpret_cast<const float4*>(Wl)[i];
        *reinterpret_cast<float4*>(&wr_s[o * PAD + k4 * 4]) =
            reinterpret_cast<const float4*>(Wr)[i];
    }

    int nl = t / OUTF, o = t % OUTF;
    for (int g = 0; g < MMG; ++g) {
        int base = blockIdx.x * (NPB * MMG) + g * NPB;   // grid 1250 -> exact
        __syncthreads();   // first iter: weights visible; later: protect x_s
        for (int i = t; i < NPB * (K / 4); i += 256) {
            int xl = i >> 4, k4 = i & 15;
            *reinterpret_cast<float4*>(&x_s[xl * PAD + k4 * 4]) =
                reinterpret_cast<const float4*>(X)[(size_t)base * (K / 4) + i];
        }
        __syncthreads();

        const float4* xv = reinterpret_cast<const float4*>(&x_s[nl * PAD]);
        const float4* lv = reinterpret_cast<const float4*>(&wl_s[o * PAD]);
        const float4* rv = reinterpret_cast<const float4*>(&wr_s[o * PAD]);
        float4 aY = {0.f, 0.f, 0.f, 0.f}, aZ = {0.f, 0.f, 0.f, 0.f};
#pragma unroll
        for (int kk = 0; kk < K / 4; ++kk) {
            float4 x4 = xv[kk], l4 = lv[kk], r4 = rv[kk];
            aY.x += x4.x * l4.x; aY.y += x4.y * l4.y;
            aY.z += x4.z * l4.z; aY.w += x4.w * l4.w;
            aZ.x += x4.x * r4.x; aZ.y += x4.y * r4.y;
            aZ.z += x4.z * r4.z; aZ.w += x4.w * r4.w;
        }
        int n = base + nl;
        Yb[(size_t)n * OUTF + o] = f2bf((aY.x + aY.y) + (aY.z + aY.w));
        Zb[(size_t)n * OUTF + o] = f2bf((aZ.x + aZ.y) + (aZ.z + aZ.w));
    }
}

// ---------------------------------------------------------------------------
// Layer-1 aggregate: half-bucket (32 nodes)/block; 16-edge main step (8 loads
// in flight) + one 8-step tail (runs x8-padded); Wl2/Wr2 prefetched to REGS
// at start, written to LDS after gather (latency hidden under gather); bias
// direct-to-reg; z1 bf16. Then fused 32-wide dual mm.
// ---------------------------------------------------------------------------
__global__ __launch_bounds__(512) void agg_layer1(const ushort_t* __restrict__ y1b,
                                                  const ushort_t* __restrict__ z1b,
                                                  const float* __restrict__ bl1,
                                                  const float* __restrict__ Wl2,
                                                  const float* __restrict__ Wr2,
                                                  const int* __restrict__ nstart,
                                                  const int* __restrict__ ndeg,
                                                  const ushort_t* __restrict__ esrc,
                                                  ushort_t* __restrict__ y2b,
                                                  ushort_t* __restrict__ z2b) {
    __shared__ ushort_t esrcS[CAP2];      //  6.1 KB
    __shared__ float hld[32 * 66];        //  8.4 KB
    __shared__ float wcat[64 * 65];       // 16.6 KB  [Wl2 | Wr2]

    int t = threadIdx.x;
    int bkt = blockIdx.x >> 1, half = blockIdx.x & 1;
    int lane = t & 63, w = t >> 6;
    int sub = lane >> 5, fp = lane & 31;

    // prefetch mm-tail constants into regs (consumed after gather)
    const float* srcW = (t < 256) ? (Wl2 + t * 8) : (Wr2 + (t - 256) * 8);
    float4 wp0 = *reinterpret_cast<const float4*>(srcW);
    float4 wp1 = *reinterpret_cast<const float4*>(srcW + 4);
    float2 bv = *reinterpret_cast<const float2*>(&bl1[2 * fp]);

    const int nb = bkt * 65;
    int sbeg = nstart[nb + 32 * half];
    int send = nstart[nb + 32 * half + 32];
    for (int i = sbeg + t; i < send; i += 512)
        esrcS[i - sbeg] = esrc[(size_t)bkt * CAP2 + i];
    __syncthreads();

    float acc0[4], acc1[4], deg[4];
#pragma unroll
    for (int k = 0; k < 4; ++k) {
        int nl = w + 8 * k;                       // 0..31 (local)
        int rb = nstart[nb + 32 * half + nl] - sbeg;
        int re = nstart[nb + 32 * half + nl + 1] - sbeg;
        deg[k] = (float)ndeg[bkt * 64 + 32 * half + nl];
        float a0 = 0.f, a1 = 0.f;
        int j = rb;
        for (; j + 15 < re; j += 16) {            // 8 loads in flight
            unsigned s0 = esrcS[j + sub],      s1 = esrcS[j + 2 + sub];
            unsigned s2 = esrcS[j + 4 + sub],  s3 = esrcS[j + 6 + sub];
            unsigned s4 = esrcS[j + 8 + sub],  s5 = esrcS[j + 10 + sub];
            unsigned s6 = esrcS[j + 12 + sub], s7 = esrcS[j + 14 + sub];
            unsigned v0 = *reinterpret_cast<const unsigned*>(&y1b[(size_t)s0 * 64 + 2 * fp]);
            unsigned v1 = *reinterpret_cast<const unsigned*>(&y1b[(size_t)s1 * 64 + 2 * fp]);
            unsigned v2 = *reinterpret_cast<const unsigned*>(&y1b[(size_t)s2 * 64 + 2 * fp]);
            unsigned v3 = *reinterpret_cast<const unsigned*>(&y1b[(size_t)s3 * 64 + 2 * fp]);
            unsigned v4 = *reinterpret_cast<const unsigned*>(&y1b[(size_t)s4 * 64 + 2 * fp]);
            unsigned v5 = *reinterpret_cast<const unsigned*>(&y1b[(size_t)s5 * 64 + 2 * fp]);
            unsigned v6 = *reinterpret_cast<const unsigned*>(&y1b[(size_t)s6 * 64 + 2 * fp]);
            unsigned v7 = *reinterpret_cast<const unsigned*>(&y1b[(size_t)s7 * 64 + 2 * fp]);
            a0 += bf2f((ushort_t)(v0 & 0xFFFF)) + bf2f((ushort_t)(v1 & 0xFFFF))
                + bf2f((ushort_t)(v2 & 0xFFFF)) + bf2f((ushort_t)(v3 & 0xFFFF))
                + bf2f((ushort_t)(v4 & 0xFFFF)) + bf2f((ushort_t)(v5 & 0xFFFF))
                + bf2f((ushort_t)(v6 & 0xFFFF)) + bf2f((ushort_t)(v7 & 0xFFFF));
            a1 += bf2f((ushort_t)(v0 >> 16)) + bf2f((ushort_t)(v1 >> 16))
                + bf2f((ushort_t)(v2 >> 16)) + bf2f((ushort_t)(v3 >> 16))
                + bf2f((ushort_t)(v4 >> 16)) + bf2f((ushort_t)(v5 >> 16))
                + bf2f((ushort_t)(v6 >> 16)) + bf2f((ushort_t)(v7 >> 16));
        }
        if (j < re) {                             // exactly one 8-step remains
            unsigned s0 = esrcS[j + sub],     s1 = esrcS[j + 2 + sub];
            unsigned s2 = esrcS[j + 4 + sub], s3 = esrcS[j + 6 + sub];
            unsigned v0 = *reinterpret_cast<const unsigned*>(&y1b[(size_t)s0 * 64 + 2 * fp]);
            unsigned v1 = *reinterpret_cast<const unsigned*>(&y1b[(size_t)s1 * 64 + 2 * fp]);
            unsigned v2 = *reinterpret_cast<const unsigned*>(&y1b[(size_t)s2 * 64 + 2 * fp]);
            unsigned v3 = *reinterpret_cast<const unsigned*>(&y1b[(size_t)s3 * 64 + 2 * fp]);
            a0 += bf2f((ushort_t)(v0 & 0xFFFF)) + bf2f((ushort_t)(v1 & 0xFFFF))
                + bf2f((ushort_t)(v2 & 0xFFFF)) + bf2f((ushort_t)(v3 & 0xFFFF));
            a1 += bf2f((ushort_t)(v0 >> 16)) + bf2f((ushort_t)(v1 >> 16))
                + bf2f((ushort_t)(v2 >> 16)) + bf2f((ushort_t)(v3 >> 16));
        }
        acc0[k] = a0;
        acc1[k] = a1;
    }

    // finalize h = relu(acc/deg + bl1 + z1) into LDS (z1 bf16)
    int nodeBase = bkt * BNODES + 32 * half;
#pragma unroll
    for (int k = 0; k < 4; ++k) {
        int nl = w + 8 * k;
        float s0 = acc0[k] + __shfl_xor(acc0[k], 32, 64);
        float s1 = acc1[k] + __shfl_xor(acc1[k], 32, 64);
        int gn = nodeBase + nl;
        if (sub == 0 && gn < N_NODES) {
            float inv = 1.f / fmaxf(deg[k], 1.f);
            unsigned zu = *reinterpret_cast<const unsigned*>(&z1b[(size_t)gn * 64 + 2 * fp]);
            float h0 = fmaxf(s0 * inv + bv.x + bf2f((ushort_t)(zu & 0xFFFF)), 0.f);
            float h1 = fmaxf(s1 * inv + bv.y + bf2f((ushort_t)(zu >> 16)), 0.f);
            *reinterpret_cast<float2*>(&hld[nl * 66 + 2 * fp]) = make_float2(h0, h1);
        }
    }

    // write prefetched weights into wcat LDS (global latency long since hidden)
    {
        int flat = (t & 255) * 8;
        int o = (flat >> 6) + ((t < 256) ? 0 : 32);
        int f = flat & 63;
        float* dstw = &wcat[o * 65 + f];
        dstw[0] = wp0.x; dstw[1] = wp0.y; dstw[2] = wp0.z; dstw[3] = wp0.w;
        dstw[4] = wp1.x; dstw[5] = wp1.y; dstw[6] = wp1.z; dstw[7] = wp1.w;
    }
    __syncthreads();

    // fused dual mm: lane l -> concat output l (l<32: y2 bf16, else z2 bf16)
#pragma unroll
    for (int kp = 0; kp < 2; ++kp) {
        int nlA = w + 16 * kp, nlB = nlA + 8;
        float sA = 0.f, sB = 0.f;
        const float* wrow = &wcat[lane * 65];
#pragma unroll 8
        for (int f = 0; f < 64; ++f) {
            float wv = wrow[f];
            sA += hld[nlA * 66 + f] * wv;
            sB += hld[nlB * 66 + f] * wv;
        }
        int gA = nodeBase + nlA, gB = nodeBase + nlB;
        int o = lane & 31;
        if (gA < N_NODES) {
            if (lane < 32) y2b[(size_t)gA * 32 + o] = f2bf(sA);
            else           z2b[(size_t)gA * 32 + o] = f2bf(sA);
        }
        if (gB < N_NODES) {
            if (lane < 32) y2b[(size_t)gB * 32 + o] = f2bf(sB);
            else           z2b[(size_t)gB * 32 + o] = f2bf(sB);
        }
    }
}

// ---------------------------------------------------------------------------
// Layer-2 aggregate: half-bucket/block, padded runs (x8), step-16 main loop
// (4 loads in flight) + one 8-step. Bias direct-to-reg; z2 bf16.
// out = mean + bl2 + z2 (f32 output).
// ---------------------------------------------------------------------------
__global__ __launch_bounds__(512) void agg_layer2(const ushort_t* __restrict__ y2b,
                                                  const ushort_t* __restrict__ z2b,
                                                  const float* __restrict__ bl2,
                                                  const int* __restrict__ nstart,
                                                  const int* __restrict__ ndeg,
                                                  const ushort_t* __restrict__ esrc,
                                                  float* __restrict__ out) {
    __shared__ ushort_t esrcS[CAP2];
    int t = threadIdx.x;
    int bkt = blockIdx.x >> 1, half = blockIdx.x & 1;
    int lane = t & 63, w = t >> 6;
    int sub4 = lane >> 4, fp = lane & 15;

    float2 bv = *reinterpret_cast<const float2*>(&bl2[2 * fp]);

    const int nb = bkt * 65;
    int sbeg = nstart[nb + 32 * half];
    int send = nstart[nb + 32 * half + 32];
    for (int i = sbeg + t; i < send; i += 512)
        esrcS[i - sbeg] = esrc[(size_t)bkt * CAP2 + i];
    __syncthreads();

    int nodeBase = bkt * BNODES + 32 * half;
#pragma unroll
    for (int k = 0; k < 4; ++k) {
        int nl = w + 8 * k;
        int rb = nstart[nb + 32 * half + nl] - sbeg;
        int re = nstart[nb + 32 * half + nl + 1] - sbeg;
        float a0 = 0.f, a1 = 0.f;
        int j = rb;
        for (; j + 15 < re; j += 16) {            // 4 loads in flight
            unsigned sA = esrcS[j + sub4],      sB = esrcS[j + 4 + sub4];
            unsigned sC = esrcS[j + 8 + sub4],  sD = esrcS[j + 12 + sub4];
            unsigned a = *reinterpret_cast<const unsigned*>(&y2b[(size_t)sA * 32 + 2 * fp]);
            unsigned bb = *reinterpret_cast<const unsigned*>(&y2b[(size_t)sB * 32 + 2 * fp]);
            unsigned c = *reinterpret_cast<const unsigned*>(&y2b[(size_t)sC * 32 + 2 * fp]);
            unsigned d = *reinterpret_cast<const unsigned*>(&y2b[(size_t)sD * 32 + 2 * fp]);
            a0 += bf2f((ushort_t)(a & 0xFFFF)) + bf2f((ushort_t)(bb & 0xFFFF))
                + bf2f((ushort_t)(c & 0xFFFF)) + bf2f((ushort_t)(d & 0xFFFF));
            a1 += bf2f((ushort_t)(a >> 16)) + bf2f((ushort_t)(bb >> 16))
                + bf2f((ushort_t)(c >> 16)) + bf2f((ushort_t)(d >> 16));
        }
        if (j < re) {                             // exactly one 8-step remains
            unsigned sA = esrcS[j + sub4], sB = esrcS[j + 4 + sub4];
            unsigned a = *reinterpret_cast<const unsigned*>(&y2b[(size_t)sA * 32 + 2 * fp]);
            unsigned bb = *reinterpret_cast<const unsigned*>(&y2b[(size_t)sB * 32 + 2 * fp]);
            a0 += bf2f((ushort_t)(a & 0xFFFF)) + bf2f((ushort_t)(bb & 0xFFFF));
            a1 += bf2f((ushort_t)(a >> 16)) + bf2f((ushort_t)(bb >> 16));
        }

        a0 += __shfl_xor(a0, 16, 64); a0 += __shfl_xor(a0, 32, 64);
        a1 += __shfl_xor(a1, 16, 64); a1 += __shfl_xor(a1, 32, 64);
        int gn = nodeBase + nl;
        if (sub4 == 0 && gn < N_NODES) {
            float inv = 1.f / fmaxf((float)ndeg[bkt * 64 + 32 * half + nl], 1.f);
            unsigned zu = *reinterpret_cast<const unsigned*>(&z2b[(size_t)gn * 32 + 2 * fp]);
            float2 ov;
            ov.x = a0 * inv + bv.x + bf2f((ushort_t)(zu & 0xFFFF));
            ov.y = a1 * inv + bv.y + bf2f((ushort_t)(zu >> 16));
            *reinterpret_cast<float2*>(&out[(size_t)gn * 32 + 2 * fp]) = ov;
        }
    }
}

extern "C" void kernel_launch(void* const* d_in, const int* in_sizes, int n_in,
                              void* d_out, int out_size, void* d_ws, size_t ws_size,
                              hipStream_t stream) {
    const float* x   = (const float*)d_in[0];
    const int*   ei  = (const int*)d_in[1];   // (2, N_EDGES) int32
    const float* Wl1 = (const float*)d_in[2];
    const float* bl1 = (const float*)d_in[3];
    const float* Wr1 = (const float*)d_in[4];
    const float* Wl2 = (const float*)d_in[5];
    const float* bl2 = (const float*)d_in[6];
    const float* Wr2 = (const float*)d_in[7];
    float* out = (float*)d_out;

    const int* src = ei;
    const int* dst = ei + N_EDGES;

    // Workspace layout (byte offsets, 16B-aligned). Total ~32.4 MB.
    // y1b/y2b carry an extra zero row at index 50000 (gather-pad target).
    char* wsb = (char*)d_ws;
    int*      cursor = (int*)(wsb + 0);              //  4 KB (zeroed)
    unsigned* ebuf   = (unsigned*)(wsb + 4096);      //  782*2560*4 = 8,007,680
    ushort_t* esrc   = (ushort_t*)(wsb + 8011776);   //  782*3072*2 = 4,804,608
    int*      nstart = (int*)(wsb + 12816384);       //  782*65*4   =   203,320
    int*      ndeg   = (int*)(wsb + 13019712);       //  782*64*4   =   200,192
    ushort_t* y1b    = (ushort_t*)(wsb + 13219904);  //  50001*64*2 = 6,400,128
    ushort_t* z1b    = (ushort_t*)(wsb + 19620032);  //  50000*64*2 = 6,400,000
    ushort_t* y2b    = (ushort_t*)(wsb + 26020032);  //  50001*32*2 = 3,200,064
    ushort_t* z2b    = (ushort_t*)(wsb + 29220096);  //  50000*32*2 = 3,200,000

    hipMemsetAsync(cursor, 0, NBUCK * sizeof(int), stream);
    hipMemsetAsync((char*)y1b + (size_t)ZROW * 64 * 2, 0, 128, stream);  // zero row
    hipMemsetAsync((char*)y2b + (size_t)ZROW * 32 * 2, 0, 64, stream);   // zero row

    scatter_direct<<<SC_NBLK, SC_BLK, 0, stream>>>(src, dst, cursor, ebuf);
    refine_sort<<<NB_USED, 256, 0, stream>>>(cursor, ebuf, esrc, nstart, ndeg);

    mm_dual64<<<1250, 256, 0, stream>>>(x, Wl1, Wr1, y1b, z1b);
    agg_layer1<<<NB_USED * 2, 512, 0, stream>>>(y1b, z1b, bl1, Wl2, Wr2, nstart, ndeg, esrc, y2b, z2b);
    agg_layer2<<<NB_USED * 2, 512, 0, stream>>>(y2b, z2b, bl2, nstart, ndeg, esrc, out);
}

// Round 11
// 183.751 us; speedup vs baseline: 1.0738x; 1.0099x over previous
//
#include <hip/hip_runtime.h>

#define N_NODES 50000
#define N_EDGES 800000

#define NBUCK   1024                 // bucket id = dst >> 6 (<= 781 used)
#define BNODES  64
#define NB_USED 782                  // ceil(50000/64)
#define CAP     2560                 // raw slots per bucket (mean 1024, sigma 32)
#define CAP2    3072                 // padded slots per bucket
#define ZROW    50000                // dummy zero row index (gather pad target)
#define SC_BLK  1024
#define SC_EPT  8
#define SC_EPB  (SC_BLK * SC_EPT)    // 8192
#define SC_NBLK ((N_EDGES + SC_EPB - 1) / SC_EPB)   // 98

typedef unsigned short ushort_t;

static __device__ __forceinline__ ushort_t f2bf(float x) {
    unsigned b = __float_as_uint(x);
    unsigned r = (b + 0x7FFFu + ((b >> 16) & 1u)) >> 16;   // RNE
    return (ushort_t)r;
}
static __device__ __forceinline__ float bf2f(ushort_t u) {
    return __uint_as_float(((unsigned)u) << 16);
}

// ---------------------------------------------------------------------------
// Direct bucket scatter into fixed-capacity bucket slabs. 8 edges/thread via
// int4 loads; LDS bucket-sort; ONE global atomic per (block,bucket); burst
// writes (~10.5 edges/run). Edge packed as (dst<<16)|src.
// ---------------------------------------------------------------------------
__global__ __launch_bounds__(SC_BLK) void scatter_direct(const int* __restrict__ src,
                                                         const int* __restrict__ dst,
                                                         int* __restrict__ cursor,
                                                         unsigned* __restrict__ ebuf) {
    __shared__ int h[NBUCK];
    __shared__ int hs[NBUCK];
    __shared__ int gbase[NBUCK];
    __shared__ int wsum[16];
    __shared__ unsigned stage[SC_EPB];   // 32 KB
    int t = threadIdx.x;
    int lane = t & 63, wid = t >> 6;
    h[t] = 0;
    __syncthreads();

    int base = blockIdx.x * SC_EPB;
    int e0 = base + t * 8;
    unsigned pk[8];
    int rk[8];
    int nv = 0;
    if (e0 + 8 <= N_EDGES) {
        int4 d0 = *reinterpret_cast<const int4*>(dst + e0);
        int4 d1 = *reinterpret_cast<const int4*>(dst + e0 + 4);
        int4 s0 = *reinterpret_cast<const int4*>(src + e0);
        int4 s1 = *reinterpret_cast<const int4*>(src + e0 + 4);
        int dd[8] = {d0.x, d0.y, d0.z, d0.w, d1.x, d1.y, d1.z, d1.w};
        int ss[8] = {s0.x, s0.y, s0.z, s0.w, s1.x, s1.y, s1.z, s1.w};
#pragma unroll
        for (int j = 0; j < 8; ++j) {
            pk[j] = ((unsigned)dd[j] << 16) | (unsigned)ss[j];
            rk[j] = atomicAdd(&h[dd[j] >> 6], 1);
        }
        nv = 8;
    } else {
        for (int j = 0; j < 8; ++j) {
            int e = e0 + j;
            if (e < N_EDGES) {
                int d = dst[e], s = src[e];
                pk[j] = ((unsigned)d << 16) | (unsigned)s;
                rk[j] = atomicAdd(&h[d >> 6], 1);
                nv = j + 1;
            }
        }
    }
    __syncthreads();

    int cnt = h[t];
    int pr = cnt;
#pragma unroll
    for (int off = 1; off < 64; off <<= 1) {
        int u = __shfl_up(pr, off, 64);
        if (lane >= off) pr += u;
    }
    if (lane == 63) wsum[wid] = pr;
    __syncthreads();
    if (t < 16) {
        int v = wsum[t], p2 = v;
#pragma unroll
        for (int off = 1; off < 16; off <<= 1) {
            int u = __shfl_up(p2, off, 16);
            if (t >= off) p2 += u;
        }
        wsum[t] = p2 - v;
    }
    __syncthreads();
    hs[t] = pr - cnt + wsum[wid];
    if (cnt) gbase[t] = atomicAdd(&cursor[t], cnt);
    __syncthreads();

#pragma unroll
    for (int j = 0; j < 8; ++j) {
        if (j < nv) {
            int b = pk[j] >> 22;
            stage[hs[b] + rk[j]] = pk[j];
        }
    }
    __syncthreads();

    int total = N_EDGES - base;
    if (total > SC_EPB) total = SC_EPB;
    for (int i = t; i < total; i += SC_BLK) {
        unsigned p = stage[i];
        int b = p >> 22;
        int idx = gbase[b] + (i - hs[b]);
        if (idx < CAP) ebuf[(size_t)b * CAP + idx] = p;
    }
}

// ---------------------------------------------------------------------------
// Per-bucket refine: counting-sort by local node id, runs padded to x8 with
// src=ZROW. Emits esrc, nstart (padded offsets), ndeg (real degrees).
// ---------------------------------------------------------------------------
__global__ __launch_bounds__(256) void refine_sort(const int* __restrict__ cursor,
                                                   const unsigned* __restrict__ ebuf,
                                                   ushort_t* __restrict__ esrc,
                                                   int* __restrict__ nstart,
                                                   int* __restrict__ ndeg) {
    __shared__ int bins[BNODES];
    __shared__ int bcur[BNODES];
    __shared__ int tot;
    __shared__ unsigned estage[CAP];
    __shared__ ushort_t esortS[CAP2];
    int t = threadIdx.x, b = blockIdx.x;

    int n = cursor[b];
    if (n > CAP) n = CAP;
    if (t < BNODES) bins[t] = 0;
    __syncthreads();

    for (int i = t; i < n; i += 256) {
        unsigned p = ebuf[(size_t)b * CAP + i];
        estage[i] = p;
        atomicAdd(&bins[(p >> 16) & 63], 1);
    }
    __syncthreads();

    if (t < 64) {
        int real = bins[t];
        int pad8 = (real + 7) & ~7;
        int pr = pad8;
#pragma unroll
        for (int off = 1; off < 64; off <<= 1) {
            int u = __shfl_up(pr, off, 64);
            if (t >= off) pr += u;
        }
        int excl = pr - pad8;
        bcur[t] = excl;
        nstart[b * 65 + t] = excl;
        ndeg[b * 64 + t] = real;
        if (t == 63) { nstart[b * 65 + 64] = pr; tot = pr; }
    }
    __syncthreads();

    for (int i = t; i < n; i += 256) {
        unsigned p = estage[i];
        esortS[atomicAdd(&bcur[(p >> 16) & 63], 1)] = (ushort_t)p;
    }
    __syncthreads();

    if (t < 64) {
        int e8 = nstart[b * 65 + t + 1];
        for (int q = bcur[t]; q < e8; ++q) esortS[q] = (ushort_t)ZROW;
    }
    __syncthreads();

    int nt = tot;
    for (int i = t; i < nt; i += 256)
        esrc[(size_t)b * CAP2 + i] = esortS[i];
}

// ---------------------------------------------------------------------------
// Dual linear (layer 1): Yb = bf16(X @ Wl^T), Zb = bf16(X @ Wr^T).
// Weights staged ONCE per block; 10 node-groups looped (40 nodes/block).
// ---------------------------------------------------------------------------
#define MMG 10
__global__ __launch_bounds__(256) void mm_dual64(const float* __restrict__ X,
                                                 const float* __restrict__ Wl,
                                                 const float* __restrict__ Wr,
                                                 ushort_t* __restrict__ Yb,
                                                 ushort_t* __restrict__ Zb) {
    constexpr int K = 64, OUTF = 64, NPB = 4, PAD = 68;
    __shared__ float wl_s[OUTF * PAD];
    __shared__ float wr_s[OUTF * PAD];
    __shared__ float x_s[NPB * PAD];
    int t = threadIdx.x;

    for (int i = t; i < OUTF * (K / 4); i += 256) {
        int o = i >> 4, k4 = i & 15;
        *reinterpret_cast<float4*>(&wl_s[o * PAD + k4 * 4]) =
            reinterpret_cast<const float4*>(Wl)[i];
        *reinterpret_cast<float4*>(&wr_s[o * PAD + k4 * 4]) =
            reinterpret_cast<const float4*>(Wr)[i];
    }

    int nl = t / OUTF, o = t % OUTF;
    for (int g = 0; g < MMG; ++g) {
        int base = blockIdx.x * (NPB * MMG) + g * NPB;   // grid 1250 -> exact
        __syncthreads();
        for (int i = t; i < NPB * (K / 4); i += 256) {
            int xl = i >> 4, k4 = i & 15;
            *reinterpret_cast<float4*>(&x_s[xl * PAD + k4 * 4]) =
                reinterpret_cast<const float4*>(X)[(size_t)base * (K / 4) + i];
        }
        __syncthreads();

        const float4* xv = reinterpret_cast<const float4*>(&x_s[nl * PAD]);
        const float4* lv = reinterpret_cast<const float4*>(&wl_s[o * PAD]);
        const float4* rv = reinterpret_cast<const float4*>(&wr_s[o * PAD]);
        float4 aY = {0.f, 0.f, 0.f, 0.f}, aZ = {0.f, 0.f, 0.f, 0.f};
#pragma unroll
        for (int kk = 0; kk < K / 4; ++kk) {
            float4 x4 = xv[kk], l4 = lv[kk], r4 = rv[kk];
            aY.x += x4.x * l4.x; aY.y += x4.y * l4.y;
            aY.z += x4.z * l4.z; aY.w += x4.w * l4.w;
            aZ.x += x4.x * r4.x; aZ.y += x4.y * r4.y;
            aZ.z += x4.z * r4.z; aZ.w += x4.w * r4.w;
        }
        int n = base + nl;
        Yb[(size_t)n * OUTF + o] = f2bf((aY.x + aY.y) + (aY.z + aY.w));
        Zb[(size_t)n * OUTF + o] = f2bf((aZ.x + aZ.y) + (aZ.z + aZ.w));
    }
}

// ---------------------------------------------------------------------------
// Layer-1 aggregate: full bucket (64 nodes)/block, wave owns 8 nodes; DUAL-RUN
// gather (2 node-runs in flight -> 8 uint2 loads = 32 edges outstanding).
// Lane: eo=lane>>4 (edge-in-quad), fp=lane&15 -> feats {4fp..4fp+3} (uint2).
// Finalize h in LDS, then fused 32-wide dual mm (Wl2/Wr2 reg-prefetched).
// ---------------------------------------------------------------------------
#define CVT2(v, a)                                                         \
    a[0] += bf2f((ushort_t)((v).x & 0xFFFF)); a[1] += bf2f((ushort_t)((v).x >> 16)); \
    a[2] += bf2f((ushort_t)((v).y & 0xFFFF)); a[3] += bf2f((ushort_t)((v).y >> 16));

__global__ __launch_bounds__(512) void agg_layer1(const ushort_t* __restrict__ y1b,
                                                  const ushort_t* __restrict__ z1b,
                                                  const float* __restrict__ bl1,
                                                  const float* __restrict__ Wl2,
                                                  const float* __restrict__ Wr2,
                                                  const int* __restrict__ nstart,
                                                  const int* __restrict__ ndeg,
                                                  const ushort_t* __restrict__ esrc,
                                                  ushort_t* __restrict__ y2b,
                                                  ushort_t* __restrict__ z2b) {
    __shared__ ushort_t esrcS[CAP2];      //  6.1 KB
    __shared__ float hld[BNODES * 68];    // 17.4 KB (float4-aligned rows)
    __shared__ float wcat[64 * 65];       // 16.6 KB  [Wl2 | Wr2]

    int t = threadIdx.x, b = blockIdx.x;
    int lane = t & 63, w = t >> 6;
    int eo = lane >> 4, fp = lane & 15;

    // prefetch mm-tail constants into regs (consumed after gather)
    const float* srcW = (t < 256) ? (Wl2 + t * 8) : (Wr2 + (t - 256) * 8);
    float4 wp0 = *reinterpret_cast<const float4*>(srcW);
    float4 wp1 = *reinterpret_cast<const float4*>(srcW + 4);
    float4 bv = *reinterpret_cast<const float4*>(&bl1[4 * fp]);

    const int nb = b * 65;
    int tot = nstart[nb + 64];
    for (int i = t; i < tot; i += 512) esrcS[i] = esrc[(size_t)b * CAP2 + i];
    __syncthreads();

    int nodeBase = b * BNODES;
#pragma unroll
    for (int kp = 0; kp < 4; ++kp) {
        int nlA = w + 8 * (2 * kp), nlB = w + 8 * (2 * kp + 1);
        int jA = nstart[nb + nlA], reA = nstart[nb + nlA + 1];
        int jB = nstart[nb + nlB], reB = nstart[nb + nlB + 1];
        float aA[4] = {0.f, 0.f, 0.f, 0.f};
        float aB[4] = {0.f, 0.f, 0.f, 0.f};

        // dual-run main: 16 edges from each run per iter (8 uint2 in flight)
        while (jA + 15 < reA && jB + 15 < reB) {
            unsigned sA0 = esrcS[jA + eo],     sA1 = esrcS[jA + 4 + eo];
            unsigned sA2 = esrcS[jA + 8 + eo], sA3 = esrcS[jA + 12 + eo];
            unsigned sB0 = esrcS[jB + eo],     sB1 = esrcS[jB + 4 + eo];
            unsigned sB2 = esrcS[jB + 8 + eo], sB3 = esrcS[jB + 12 + eo];
            uint2 vA0 = *reinterpret_cast<const uint2*>(&y1b[(size_t)sA0 * 64 + 4 * fp]);
            uint2 vA1 = *reinterpret_cast<const uint2*>(&y1b[(size_t)sA1 * 64 + 4 * fp]);
            uint2 vA2 = *reinterpret_cast<const uint2*>(&y1b[(size_t)sA2 * 64 + 4 * fp]);
            uint2 vA3 = *reinterpret_cast<const uint2*>(&y1b[(size_t)sA3 * 64 + 4 * fp]);
            uint2 vB0 = *reinterpret_cast<const uint2*>(&y1b[(size_t)sB0 * 64 + 4 * fp]);
            uint2 vB1 = *reinterpret_cast<const uint2*>(&y1b[(size_t)sB1 * 64 + 4 * fp]);
            uint2 vB2 = *reinterpret_cast<const uint2*>(&y1b[(size_t)sB2 * 64 + 4 * fp]);
            uint2 vB3 = *reinterpret_cast<const uint2*>(&y1b[(size_t)sB3 * 64 + 4 * fp]);
            CVT2(vA0, aA) CVT2(vA1, aA) CVT2(vA2, aA) CVT2(vA3, aA)
            CVT2(vB0, aB) CVT2(vB1, aB) CVT2(vB2, aB) CVT2(vB3, aB)
            jA += 16; jB += 16;
        }
        // finish A
        while (jA + 15 < reA) {
            unsigned s0 = esrcS[jA + eo],     s1 = esrcS[jA + 4 + eo];
            unsigned s2 = esrcS[jA + 8 + eo], s3 = esrcS[jA + 12 + eo];
            uint2 v0 = *reinterpret_cast<const uint2*>(&y1b[(size_t)s0 * 64 + 4 * fp]);
            uint2 v1 = *reinterpret_cast<const uint2*>(&y1b[(size_t)s1 * 64 + 4 * fp]);
            uint2 v2 = *reinterpret_cast<const uint2*>(&y1b[(size_t)s2 * 64 + 4 * fp]);
            uint2 v3 = *reinterpret_cast<const uint2*>(&y1b[(size_t)s3 * 64 + 4 * fp]);
            CVT2(v0, aA) CVT2(v1, aA) CVT2(v2, aA) CVT2(v3, aA)
            jA += 16;
        }
        if (jA < reA) {                       // exactly 8 edges remain
            unsigned s0 = esrcS[jA + eo], s1 = esrcS[jA + 4 + eo];
            uint2 v0 = *reinterpret_cast<const uint2*>(&y1b[(size_t)s0 * 64 + 4 * fp]);
            uint2 v1 = *reinterpret_cast<const uint2*>(&y1b[(size_t)s1 * 64 + 4 * fp]);
            CVT2(v0, aA) CVT2(v1, aA)
        }
        // finish B
        while (jB + 15 < reB) {
            unsigned s0 = esrcS[jB + eo],     s1 = esrcS[jB + 4 + eo];
            unsigned s2 = esrcS[jB + 8 + eo], s3 = esrcS[jB + 12 + eo];
            uint2 v0 = *reinterpret_cast<const uint2*>(&y1b[(size_t)s0 * 64 + 4 * fp]);
            uint2 v1 = *reinterpret_cast<const uint2*>(&y1b[(size_t)s1 * 64 + 4 * fp]);
            uint2 v2 = *reinterpret_cast<const uint2*>(&y1b[(size_t)s2 * 64 + 4 * fp]);
            uint2 v3 = *reinterpret_cast<const uint2*>(&y1b[(size_t)s3 * 64 + 4 * fp]);
            CVT2(v0, aB) CVT2(v1, aB) CVT2(v2, aB) CVT2(v3, aB)
            jB += 16;
        }
        if (jB < reB) {
            unsigned s0 = esrcS[jB + eo], s1 = esrcS[jB + 4 + eo];
            uint2 v0 = *reinterpret_cast<const uint2*>(&y1b[(size_t)s0 * 64 + 4 * fp]);
            uint2 v1 = *reinterpret_cast<const uint2*>(&y1b[(size_t)s1 * 64 + 4 * fp]);
            CVT2(v0, aB) CVT2(v1, aB)
        }

        // reduce across eo groups; eo==0 lanes finalize h = relu(mean+b+z)
#pragma unroll
        for (int i = 0; i < 4; ++i) {
            aA[i] += __shfl_xor(aA[i], 16, 64); aA[i] += __shfl_xor(aA[i], 32, 64);
            aB[i] += __shfl_xor(aB[i], 16, 64); aB[i] += __shfl_xor(aB[i], 32, 64);
        }
        if (eo == 0) {
            int gA = nodeBase + nlA, gB = nodeBase + nlB;
            if (gA < N_NODES) {
                float inv = 1.f / fmaxf((float)ndeg[b * 64 + nlA], 1.f);
                uint2 zu = *reinterpret_cast<const uint2*>(&z1b[(size_t)gA * 64 + 4 * fp]);
                float4 hv;
                hv.x = fmaxf(aA[0] * inv + bv.x + bf2f((ushort_t)(zu.x & 0xFFFF)), 0.f);
                hv.y = fmaxf(aA[1] * inv + bv.y + bf2f((ushort_t)(zu.x >> 16)), 0.f);
                hv.z = fmaxf(aA[2] * inv + bv.z + bf2f((ushort_t)(zu.y & 0xFFFF)), 0.f);
                hv.w = fmaxf(aA[3] * inv + bv.w + bf2f((ushort_t)(zu.y >> 16)), 0.f);
                *reinterpret_cast<float4*>(&hld[nlA * 68 + 4 * fp]) = hv;
            }
            if (gB < N_NODES) {
                float inv = 1.f / fmaxf((float)ndeg[b * 64 + nlB], 1.f);
                uint2 zu = *reinterpret_cast<const uint2*>(&z1b[(size_t)gB * 64 + 4 * fp]);
                float4 hv;
                hv.x = fmaxf(aB[0] * inv + bv.x + bf2f((ushort_t)(zu.x & 0xFFFF)), 0.f);
                hv.y = fmaxf(aB[1] * inv + bv.y + bf2f((ushort_t)(zu.x >> 16)), 0.f);
                hv.z = fmaxf(aB[2] * inv + bv.z + bf2f((ushort_t)(zu.y & 0xFFFF)), 0.f);
                hv.w = fmaxf(aB[3] * inv + bv.w + bf2f((ushort_t)(zu.y >> 16)), 0.f);
                *reinterpret_cast<float4*>(&hld[nlB * 68 + 4 * fp]) = hv;
            }
        }
    }

    // write prefetched weights into wcat LDS (latency hidden under gather)
    {
        int flat = (t & 255) * 8;
        int o = (flat >> 6) + ((t < 256) ? 0 : 32);
        int f = flat & 63;
        float* dstw = &wcat[o * 65 + f];
        dstw[0] = wp0.x; dstw[1] = wp0.y; dstw[2] = wp0.z; dstw[3] = wp0.w;
        dstw[4] = wp1.x; dstw[5] = wp1.y; dstw[6] = wp1.z; dstw[7] = wp1.w;
    }
    __syncthreads();

    // fused dual mm: lane l -> concat output l (l<32: y2 bf16, else z2 bf16)
#pragma unroll
    for (int kp = 0; kp < 4; ++kp) {
        int nlA = w + 8 * (2 * kp), nlB = nlA + 8;
        float sA = 0.f, sB = 0.f;
        const float* wrow = &wcat[lane * 65];
#pragma unroll 8
        for (int f = 0; f < 64; ++f) {
            float wv = wrow[f];
            sA += hld[nlA * 68 + f] * wv;
            sB += hld[nlB * 68 + f] * wv;
        }
        int gA = nodeBase + nlA, gB = nodeBase + nlB;
        int o = lane & 31;
        if (gA < N_NODES) {
            if (lane < 32) y2b[(size_t)gA * 32 + o] = f2bf(sA);
            else           z2b[(size_t)gA * 32 + o] = f2bf(sA);
        }
        if (gB < N_NODES) {
            if (lane < 32) y2b[(size_t)gB * 32 + o] = f2bf(sB);
            else           z2b[(size_t)gB * 32 + o] = f2bf(sB);
        }
    }
}

// ---------------------------------------------------------------------------
// Layer-2 aggregate: full bucket/block, DUAL-RUN gather (4 uint2 loads =
// 32 edges outstanding). Lane: eo=lane>>3 (8 edges/step), fp=lane&7 ->
// feats {4fp..4fp+3}. out = mean + bl2 + z2 (f32, float4 stores).
// ---------------------------------------------------------------------------
__global__ __launch_bounds__(512) void agg_layer2(const ushort_t* __restrict__ y2b,
                                                  const ushort_t* __restrict__ z2b,
                                                  const float* __restrict__ bl2,
                                                  const int* __restrict__ nstart,
                                                  const int* __restrict__ ndeg,
                                                  const ushort_t* __restrict__ esrc,
                                                  float* __restrict__ out) {
    __shared__ ushort_t esrcS[CAP2];
    int t = threadIdx.x, b = blockIdx.x;
    int lane = t & 63, w = t >> 6;
    int eo = lane >> 3, fp = lane & 7;

    float4 bv = *reinterpret_cast<const float4*>(&bl2[4 * fp]);

    const int nb = b * 65;
    int tot = nstart[nb + 64];
    for (int i = t; i < tot; i += 512) esrcS[i] = esrc[(size_t)b * CAP2 + i];
    __syncthreads();

    int nodeBase = b * BNODES;
#pragma unroll
    for (int kp = 0; kp < 4; ++kp) {
        int nlA = w + 8 * (2 * kp), nlB = w + 8 * (2 * kp + 1);
        int jA = nstart[nb + nlA], reA = nstart[nb + nlA + 1];
        int jB = nstart[nb + nlB], reB = nstart[nb + nlB + 1];
        float aA[4] = {0.f, 0.f, 0.f, 0.f};
        float aB[4] = {0.f, 0.f, 0.f, 0.f};

        while (jA + 15 < reA && jB + 15 < reB) {
            unsigned sA0 = esrcS[jA + eo], sA1 = esrcS[jA + 8 + eo];
            unsigned sB0 = esrcS[jB + eo], sB1 = esrcS[jB + 8 + eo];
            uint2 vA0 = *reinterpret_cast<const uint2*>(&y2b[(size_t)sA0 * 32 + 4 * fp]);
            uint2 vA1 = *reinterpret_cast<const uint2*>(&y2b[(size_t)sA1 * 32 + 4 * fp]);
            uint2 vB0 = *reinterpret_cast<const uint2*>(&y2b[(size_t)sB0 * 32 + 4 * fp]);
            uint2 vB1 = *reinterpret_cast<const uint2*>(&y2b[(size_t)sB1 * 32 + 4 * fp]);
            CVT2(vA0, aA) CVT2(vA1, aA) CVT2(vB0, aB) CVT2(vB1, aB)
            jA += 16; jB += 16;
        }
        while (jA + 15 < reA) {
            unsigned s0 = esrcS[jA + eo], s1 = esrcS[jA + 8 + eo];
            uint2 v0 = *reinterpret_cast<const uint2*>(&y2b[(size_t)s0 * 32 + 4 * fp]);
            uint2 v1 = *reinterpret_cast<const uint2*>(&y2b[(size_t)s1 * 32 + 4 * fp]);
            CVT2(v0, aA) CVT2(v1, aA)
            jA += 16;
        }
        if (jA < reA) {                      // exactly 8 edges remain
            unsigned s0 = esrcS[jA + eo];
            uint2 v0 = *reinterpret_cast<const uint2*>(&y2b[(size_t)s0 * 32 + 4 * fp]);
            CVT2(v0, aA)
        }
        while (jB + 15 < reB) {
            unsigned s0 = esrcS[jB + eo], s1 = esrcS[jB + 8 + eo];
            uint2 v0 = *reinterpret_cast<const uint2*>(&y2b[(size_t)s0 * 32 + 4 * fp]);
            uint2 v1 = *reinterpret_cast<const uint2*>(&y2b[(size_t)s1 * 32 + 4 * fp]);
            CVT2(v0, aB) CVT2(v1, aB)
            jB += 16;
        }
        if (jB < reB) {
            unsigned s0 = esrcS[jB + eo];
            uint2 v0 = *reinterpret_cast<const uint2*>(&y2b[(size_t)s0 * 32 + 4 * fp]);
            CVT2(v0, aB)
        }

#pragma unroll
        for (int i = 0; i < 4; ++i) {
            aA[i] += __shfl_xor(aA[i], 8, 64);
            aA[i] += __shfl_xor(aA[i], 16, 64);
            aA[i] += __shfl_xor(aA[i], 32, 64);
            aB[i] += __shfl_xor(aB[i], 8, 64);
            aB[i] += __shfl_xor(aB[i], 16, 64);
            aB[i] += __shfl_xor(aB[i], 32, 64);
        }
        if (eo == 0) {
            int gA = nodeBase + nlA, gB = nodeBase + nlB;
            if (gA < N_NODES) {
                float inv = 1.f / fmaxf((float)ndeg[b * 64 + nlA], 1.f);
                uint2 zu = *reinterpret_cast<const uint2*>(&z2b[(size_t)gA * 32 + 4 * fp]);
                float4 ov;
                ov.x = aA[0] * inv + bv.x + bf2f((ushort_t)(zu.x & 0xFFFF));
                ov.y = aA[1] * inv + bv.y + bf2f((ushort_t)(zu.x >> 16));
                ov.z = aA[2] * inv + bv.z + bf2f((ushort_t)(zu.y & 0xFFFF));
                ov.w = aA[3] * inv + bv.w + bf2f((ushort_t)(zu.y >> 16));
                *reinterpret_cast<float4*>(&out[(size_t)gA * 32 + 4 * fp]) = ov;
            }
            if (gB < N_NODES) {
                float inv = 1.f / fmaxf((float)ndeg[b * 64 + nlB], 1.f);
                uint2 zu = *reinterpret_cast<const uint2*>(&z2b[(size_t)gB * 32 + 4 * fp]);
                float4 ov;
                ov.x = aB[0] * inv + bv.x + bf2f((ushort_t)(zu.x & 0xFFFF));
                ov.y = aB[1] * inv + bv.y + bf2f((ushort_t)(zu.x >> 16));
                ov.z = aB[2] * inv + bv.z + bf2f((ushort_t)(zu.y & 0xFFFF));
                ov.w = aB[3] * inv + bv.w + bf2f((ushort_t)(zu.y >> 16));
                *reinterpret_cast<float4*>(&out[(size_t)gB * 32 + 4 * fp]) = ov;
            }
        }
    }
}

extern "C" void kernel_launch(void* const* d_in, const int* in_sizes, int n_in,
                              void* d_out, int out_size, void* d_ws, size_t ws_size,
                              hipStream_t stream) {
    const float* x   = (const float*)d_in[0];
    const int*   ei  = (const int*)d_in[1];   // (2, N_EDGES) int32
    const float* Wl1 = (const float*)d_in[2];
    const float* bl1 = (const float*)d_in[3];
    const float* Wr1 = (const float*)d_in[4];
    const float* Wl2 = (const float*)d_in[5];
    const float* bl2 = (const float*)d_in[6];
    const float* Wr2 = (const float*)d_in[7];
    float* out = (float*)d_out;

    const int* src = ei;
    const int* dst = ei + N_EDGES;

    // Workspace layout (byte offsets, 16B-aligned). Total ~32.4 MB.
    // y1b/y2b carry an extra zero row at index 50000 (gather-pad target).
    char* wsb = (char*)d_ws;
    int*      cursor = (int*)(wsb + 0);              //  4 KB (zeroed)
    unsigned* ebuf   = (unsigned*)(wsb + 4096);      //  782*2560*4 = 8,007,680
    ushort_t* esrc   = (ushort_t*)(wsb + 8011776);   //  782*3072*2 = 4,804,608
    int*      nstart = (int*)(wsb + 12816384);       //  782*65*4   =   203,320
    int*      ndeg   = (int*)(wsb + 13019712);       //  782*64*4   =   200,192
    ushort_t* y1b    = (ushort_t*)(wsb + 13219904);  //  50001*64*2 = 6,400,128
    ushort_t* z1b    = (ushort_t*)(wsb + 19620032);  //  50000*64*2 = 6,400,000
    ushort_t* y2b    = (ushort_t*)(wsb + 26020032);  //  50001*32*2 = 3,200,064
    ushort_t* z2b    = (ushort_t*)(wsb + 29220096);  //  50000*32*2 = 3,200,000

    hipMemsetAsync(cursor, 0, NBUCK * sizeof(int), stream);
    hipMemsetAsync((char*)y1b + (size_t)ZROW * 64 * 2, 0, 128, stream);  // zero row
    hipMemsetAsync((char*)y2b + (size_t)ZROW * 32 * 2, 0, 64, stream);   // zero row

    scatter_direct<<<SC_NBLK, SC_BLK, 0, stream>>>(src, dst, cursor, ebuf);
    refine_sort<<<NB_USED, 256, 0, stream>>>(cursor, ebuf, esrc, nstart, ndeg);

    mm_dual64<<<1250, 256, 0, stream>>>(x, Wl1, Wr1, y1b, z1b);
    agg_layer1<<<NB_USED, 512, 0, stream>>>(y1b, z1b, bl1, Wl2, Wr2, nstart, ndeg, esrc, y2b, z2b);
    agg_layer2<<<NB_USED, 512, 0, stream>>>(y2b, z2b, bl2, nstart, ndeg, esrc, out);
}

// Round 12
// 173.324 us; speedup vs baseline: 1.1384x; 1.0602x over previous
//
#include <hip/hip_runtime.h>

#define N_NODES 50000
#define N_EDGES 800000

#define NBUCK   1024                 // bucket id = dst >> 6 (<= 781 used)
#define BNODES  64
#define NB_USED 782                  // ceil(50000/64)
#define CAP     2560                 // raw slots per bucket (mean 1024, sigma 32)
#define CAP2    3072                 // padded slots per bucket
#define ZROW    50000                // dummy zero row index (gather pad target)
#define SC_BLK  1024
#define SC_EPT  8
#define SC_EPB  (SC_BLK * SC_EPT)    // 8192
#define SC_NBLK ((N_EDGES + SC_EPB - 1) / SC_EPB)   // 98
#define MM_NBLK 625                  // 80 nodes/block * 625 = 50000
#define MM_NPB  16                   // nodes per group
#define MM_G    5                    // groups per block

typedef unsigned short ushort_t;

static __device__ __forceinline__ ushort_t f2bf(float x) {
    unsigned b = __float_as_uint(x);
    unsigned r = (b + 0x7FFFu + ((b >> 16) & 1u)) >> 16;   // RNE
    return (ushort_t)r;
}
static __device__ __forceinline__ float bf2f(ushort_t u) {
    return __uint_as_float(((unsigned)u) << 16);
}

// ---------------------------------------------------------------------------
// FUSED kernel: blocks [0,98) = bucket scatter; blocks [98,723) = dual linear
// (y1=bf16(x@Wl1^T), z1=bf16(x@Wr1^T)). Independent work overlapped in one
// dispatch; LDS manually overlaid (scatter 45.1 KB / mm 39.2 KB).
// mm-block 0 also zeroes the ZROW pad rows of y1b/y2b (replaces 2 memsets).
// ---------------------------------------------------------------------------
__global__ __launch_bounds__(1024) void scatter_mm(const int* __restrict__ src,
                                                   const int* __restrict__ dst,
                                                   int* __restrict__ cursor,
                                                   unsigned* __restrict__ ebuf,
                                                   const float* __restrict__ X,
                                                   const float* __restrict__ Wl,
                                                   const float* __restrict__ Wr,
                                                   ushort_t* __restrict__ Yb,
                                                   ushort_t* __restrict__ Zb,
                                                   ushort_t* __restrict__ Y2pad) {
    __shared__ int smem[11392];          // 45568 B shared by both roles
    int t = threadIdx.x;

    if (blockIdx.x < SC_NBLK) {
        // ---------------- scatter role ----------------
        int* h      = smem;              // 1024
        int* hs     = smem + 1024;       // 1024
        int* gbase  = smem + 2048;       // 1024
        int* wsum   = smem + 3072;       // 16
        unsigned* stage = (unsigned*)(smem + 3088);   // 8192 u32 (32 KB)

        int lane = t & 63, wid = t >> 6;
        h[t] = 0;
        __syncthreads();

        int base = blockIdx.x * SC_EPB;
        int e0 = base + t * 8;
        unsigned pk[8];
        int rk[8];
        int nv = 0;
        if (e0 + 8 <= N_EDGES) {
            int4 d0 = *reinterpret_cast<const int4*>(dst + e0);
            int4 d1 = *reinterpret_cast<const int4*>(dst + e0 + 4);
            int4 s0 = *reinterpret_cast<const int4*>(src + e0);
            int4 s1 = *reinterpret_cast<const int4*>(src + e0 + 4);
            int dd[8] = {d0.x, d0.y, d0.z, d0.w, d1.x, d1.y, d1.z, d1.w};
            int ss[8] = {s0.x, s0.y, s0.z, s0.w, s1.x, s1.y, s1.z, s1.w};
#pragma unroll
            for (int j = 0; j < 8; ++j) {
                pk[j] = ((unsigned)dd[j] << 16) | (unsigned)ss[j];
                rk[j] = atomicAdd(&h[dd[j] >> 6], 1);
            }
            nv = 8;
        } else {
            for (int j = 0; j < 8; ++j) {
                int e = e0 + j;
                if (e < N_EDGES) {
                    int d = dst[e], s = src[e];
                    pk[j] = ((unsigned)d << 16) | (unsigned)s;
                    rk[j] = atomicAdd(&h[d >> 6], 1);
                    nv = j + 1;
                }
            }
        }
        __syncthreads();

        int cnt = h[t];
        int pr = cnt;
#pragma unroll
        for (int off = 1; off < 64; off <<= 1) {
            int u = __shfl_up(pr, off, 64);
            if (lane >= off) pr += u;
        }
        if (lane == 63) wsum[wid] = pr;
        __syncthreads();
        if (t < 16) {
            int v = wsum[t], p2 = v;
#pragma unroll
            for (int off = 1; off < 16; off <<= 1) {
                int u = __shfl_up(p2, off, 16);
                if (t >= off) p2 += u;
            }
            wsum[t] = p2 - v;
        }
        __syncthreads();
        hs[t] = pr - cnt + wsum[wid];
        if (cnt) gbase[t] = atomicAdd(&cursor[t], cnt);
        __syncthreads();

#pragma unroll
        for (int j = 0; j < 8; ++j) {
            if (j < nv) {
                int b = pk[j] >> 22;
                stage[hs[b] + rk[j]] = pk[j];
            }
        }
        __syncthreads();

        int total = N_EDGES - base;
        if (total > SC_EPB) total = SC_EPB;
        for (int i = t; i < total; i += SC_BLK) {
            unsigned p = stage[i];
            int b = p >> 22;
            int idx = gbase[b] + (i - hs[b]);
            if (idx < CAP) ebuf[(size_t)b * CAP + idx] = p;
        }
    } else {
        // ---------------- mm role ----------------
        float* wl_s = (float*)smem;          // 64*68 = 4352 f
        float* wr_s = wl_s + 64 * 68;        // 4352 f
        float* x_s  = wr_s + 64 * 68;        // 16*68 = 1088 f  (total 39168 B)
        int bmm = blockIdx.x - SC_NBLK;

        for (int i = t; i < 64 * 16; i += 1024) {     // 64 rows x 16 float4
            int o = i >> 4, k4 = i & 15;
            *reinterpret_cast<float4*>(&wl_s[o * 68 + k4 * 4]) =
                reinterpret_cast<const float4*>(Wl)[i];
            *reinterpret_cast<float4*>(&wr_s[o * 68 + k4 * 4]) =
                reinterpret_cast<const float4*>(Wr)[i];
        }

        int nl = t >> 6, o = t & 63;
        for (int g = 0; g < MM_G; ++g) {
            int base = bmm * (MM_NPB * MM_G) + g * MM_NPB;   // exact coverage
            __syncthreads();   // g=0: weights visible; later: protect x_s
            for (int i = t; i < MM_NPB * 16; i += 1024) {
                int xl = i >> 4, k4 = i & 15;
                *reinterpret_cast<float4*>(&x_s[xl * 68 + k4 * 4]) =
                    reinterpret_cast<const float4*>(X)[(size_t)base * 16 + i];
            }
            __syncthreads();

            const float4* xv = reinterpret_cast<const float4*>(&x_s[nl * 68]);
            const float4* lv = reinterpret_cast<const float4*>(&wl_s[o * 68]);
            const float4* rv = reinterpret_cast<const float4*>(&wr_s[o * 68]);
            float4 aY = {0.f, 0.f, 0.f, 0.f}, aZ = {0.f, 0.f, 0.f, 0.f};
#pragma unroll
            for (int kk = 0; kk < 16; ++kk) {
                float4 x4 = xv[kk], l4 = lv[kk], r4 = rv[kk];
                aY.x += x4.x * l4.x; aY.y += x4.y * l4.y;
                aY.z += x4.z * l4.z; aY.w += x4.w * l4.w;
                aZ.x += x4.x * r4.x; aZ.y += x4.y * r4.y;
                aZ.z += x4.z * r4.z; aZ.w += x4.w * r4.w;
            }
            int n = base + nl;
            Yb[(size_t)n * 64 + o] = f2bf((aY.x + aY.y) + (aY.z + aY.w));
            Zb[(size_t)n * 64 + o] = f2bf((aZ.x + aZ.y) + (aZ.z + aZ.w));
        }

        if (bmm == 0) {                      // zero pad rows (replaces memsets)
            if (t < 64) Yb[(size_t)ZROW * 64 + t] = 0;
            if (t < 32) Y2pad[(size_t)ZROW * 32 + t] = 0;
        }
    }
}

// ---------------------------------------------------------------------------
// Per-bucket refine: counting-sort by local node id, runs padded to x8 with
// src=ZROW. Emits esrc, nstart (padded offsets), ndeg (real degrees).
// ---------------------------------------------------------------------------
__global__ __launch_bounds__(256) void refine_sort(const int* __restrict__ cursor,
                                                   const unsigned* __restrict__ ebuf,
                                                   ushort_t* __restrict__ esrc,
                                                   int* __restrict__ nstart,
                                                   int* __restrict__ ndeg) {
    __shared__ int bins[BNODES];
    __shared__ int bcur[BNODES];
    __shared__ int tot;
    __shared__ unsigned estage[CAP];
    __shared__ ushort_t esortS[CAP2];
    int t = threadIdx.x, b = blockIdx.x;

    int n = cursor[b];
    if (n > CAP) n = CAP;
    if (t < BNODES) bins[t] = 0;
    __syncthreads();

    for (int i = t; i < n; i += 256) {
        unsigned p = ebuf[(size_t)b * CAP + i];
        estage[i] = p;
        atomicAdd(&bins[(p >> 16) & 63], 1);
    }
    __syncthreads();

    if (t < 64) {
        int real = bins[t];
        int pad8 = (real + 7) & ~7;
        int pr = pad8;
#pragma unroll
        for (int off = 1; off < 64; off <<= 1) {
            int u = __shfl_up(pr, off, 64);
            if (t >= off) pr += u;
        }
        int excl = pr - pad8;
        bcur[t] = excl;
        nstart[b * 65 + t] = excl;
        ndeg[b * 64 + t] = real;
        if (t == 63) { nstart[b * 65 + 64] = pr; tot = pr; }
    }
    __syncthreads();

    for (int i = t; i < n; i += 256) {
        unsigned p = estage[i];
        esortS[atomicAdd(&bcur[(p >> 16) & 63], 1)] = (ushort_t)p;
    }
    __syncthreads();

    if (t < 64) {
        int e8 = nstart[b * 65 + t + 1];
        for (int q = bcur[t]; q < e8; ++q) esortS[q] = (ushort_t)ZROW;
    }
    __syncthreads();

    int nt = tot;
    for (int i = t; i < nt; i += 256)
        esrc[(size_t)b * CAP2 + i] = esortS[i];
}

// ---------------------------------------------------------------------------
// Layer-1 aggregate (unchanged r11): full bucket/block, dual-run gather,
// finalize h in LDS, fused 32-wide dual mm (Wl2/Wr2 reg-prefetched).
// ---------------------------------------------------------------------------
#define CVT2(v, a)                                                         \
    a[0] += bf2f((ushort_t)((v).x & 0xFFFF)); a[1] += bf2f((ushort_t)((v).x >> 16)); \
    a[2] += bf2f((ushort_t)((v).y & 0xFFFF)); a[3] += bf2f((ushort_t)((v).y >> 16));

__global__ __launch_bounds__(512) void agg_layer1(const ushort_t* __restrict__ y1b,
                                                  const ushort_t* __restrict__ z1b,
                                                  const float* __restrict__ bl1,
                                                  const float* __restrict__ Wl2,
                                                  const float* __restrict__ Wr2,
                                                  const int* __restrict__ nstart,
                                                  const int* __restrict__ ndeg,
                                                  const ushort_t* __restrict__ esrc,
                                                  ushort_t* __restrict__ y2b,
                                                  ushort_t* __restrict__ z2b) {
    __shared__ ushort_t esrcS[CAP2];
    __shared__ float hld[BNODES * 68];
    __shared__ float wcat[64 * 65];

    int t = threadIdx.x, b = blockIdx.x;
    int lane = t & 63, w = t >> 6;
    int eo = lane >> 4, fp = lane & 15;

    const float* srcW = (t < 256) ? (Wl2 + t * 8) : (Wr2 + (t - 256) * 8);
    float4 wp0 = *reinterpret_cast<const float4*>(srcW);
    float4 wp1 = *reinterpret_cast<const float4*>(srcW + 4);
    float4 bv = *reinterpret_cast<const float4*>(&bl1[4 * fp]);

    const int nb = b * 65;
    int tot = nstart[nb + 64];
    for (int i = t; i < tot; i += 512) esrcS[i] = esrc[(size_t)b * CAP2 + i];
    __syncthreads();

    int nodeBase = b * BNODES;
#pragma unroll
    for (int kp = 0; kp < 4; ++kp) {
        int nlA = w + 8 * (2 * kp), nlB = w + 8 * (2 * kp + 1);
        int jA = nstart[nb + nlA], reA = nstart[nb + nlA + 1];
        int jB = nstart[nb + nlB], reB = nstart[nb + nlB + 1];
        float aA[4] = {0.f, 0.f, 0.f, 0.f};
        float aB[4] = {0.f, 0.f, 0.f, 0.f};

        while (jA + 15 < reA && jB + 15 < reB) {
            unsigned sA0 = esrcS[jA + eo],     sA1 = esrcS[jA + 4 + eo];
            unsigned sA2 = esrcS[jA + 8 + eo], sA3 = esrcS[jA + 12 + eo];
            unsigned sB0 = esrcS[jB + eo],     sB1 = esrcS[jB + 4 + eo];
            unsigned sB2 = esrcS[jB + 8 + eo], sB3 = esrcS[jB + 12 + eo];
            uint2 vA0 = *reinterpret_cast<const uint2*>(&y1b[(size_t)sA0 * 64 + 4 * fp]);
            uint2 vA1 = *reinterpret_cast<const uint2*>(&y1b[(size_t)sA1 * 64 + 4 * fp]);
            uint2 vA2 = *reinterpret_cast<const uint2*>(&y1b[(size_t)sA2 * 64 + 4 * fp]);
            uint2 vA3 = *reinterpret_cast<const uint2*>(&y1b[(size_t)sA3 * 64 + 4 * fp]);
            uint2 vB0 = *reinterpret_cast<const uint2*>(&y1b[(size_t)sB0 * 64 + 4 * fp]);
            uint2 vB1 = *reinterpret_cast<const uint2*>(&y1b[(size_t)sB1 * 64 + 4 * fp]);
            uint2 vB2 = *reinterpret_cast<const uint2*>(&y1b[(size_t)sB2 * 64 + 4 * fp]);
            uint2 vB3 = *reinterpret_cast<const uint2*>(&y1b[(size_t)sB3 * 64 + 4 * fp]);
            CVT2(vA0, aA) CVT2(vA1, aA) CVT2(vA2, aA) CVT2(vA3, aA)
            CVT2(vB0, aB) CVT2(vB1, aB) CVT2(vB2, aB) CVT2(vB3, aB)
            jA += 16; jB += 16;
        }
        while (jA + 15 < reA) {
            unsigned s0 = esrcS[jA + eo],     s1 = esrcS[jA + 4 + eo];
            unsigned s2 = esrcS[jA + 8 + eo], s3 = esrcS[jA + 12 + eo];
            uint2 v0 = *reinterpret_cast<const uint2*>(&y1b[(size_t)s0 * 64 + 4 * fp]);
            uint2 v1 = *reinterpret_cast<const uint2*>(&y1b[(size_t)s1 * 64 + 4 * fp]);
            uint2 v2 = *reinterpret_cast<const uint2*>(&y1b[(size_t)s2 * 64 + 4 * fp]);
            uint2 v3 = *reinterpret_cast<const uint2*>(&y1b[(size_t)s3 * 64 + 4 * fp]);
            CVT2(v0, aA) CVT2(v1, aA) CVT2(v2, aA) CVT2(v3, aA)
            jA += 16;
        }
        if (jA < reA) {
            unsigned s0 = esrcS[jA + eo], s1 = esrcS[jA + 4 + eo];
            uint2 v0 = *reinterpret_cast<const uint2*>(&y1b[(size_t)s0 * 64 + 4 * fp]);
            uint2 v1 = *reinterpret_cast<const uint2*>(&y1b[(size_t)s1 * 64 + 4 * fp]);
            CVT2(v0, aA) CVT2(v1, aA)
        }
        while (jB + 15 < reB) {
            unsigned s0 = esrcS[jB + eo],     s1 = esrcS[jB + 4 + eo];
            unsigned s2 = esrcS[jB + 8 + eo], s3 = esrcS[jB + 12 + eo];
            uint2 v0 = *reinterpret_cast<const uint2*>(&y1b[(size_t)s0 * 64 + 4 * fp]);
            uint2 v1 = *reinterpret_cast<const uint2*>(&y1b[(size_t)s1 * 64 + 4 * fp]);
            uint2 v2 = *reinterpret_cast<const uint2*>(&y1b[(size_t)s2 * 64 + 4 * fp]);
            uint2 v3 = *reinterpret_cast<const uint2*>(&y1b[(size_t)s3 * 64 + 4 * fp]);
            CVT2(v0, aB) CVT2(v1, aB) CVT2(v2, aB) CVT2(v3, aB)
            jB += 16;
        }
        if (jB < reB) {
            unsigned s0 = esrcS[jB + eo], s1 = esrcS[jB + 4 + eo];
            uint2 v0 = *reinterpret_cast<const uint2*>(&y1b[(size_t)s0 * 64 + 4 * fp]);
            uint2 v1 = *reinterpret_cast<const uint2*>(&y1b[(size_t)s1 * 64 + 4 * fp]);
            CVT2(v0, aB) CVT2(v1, aB)
        }

#pragma unroll
        for (int i = 0; i < 4; ++i) {
            aA[i] += __shfl_xor(aA[i], 16, 64); aA[i] += __shfl_xor(aA[i], 32, 64);
            aB[i] += __shfl_xor(aB[i], 16, 64); aB[i] += __shfl_xor(aB[i], 32, 64);
        }
        if (eo == 0) {
            int gA = nodeBase + nlA, gB = nodeBase + nlB;
            if (gA < N_NODES) {
                float inv = 1.f / fmaxf((float)ndeg[b * 64 + nlA], 1.f);
                uint2 zu = *reinterpret_cast<const uint2*>(&z1b[(size_t)gA * 64 + 4 * fp]);
                float4 hv;
                hv.x = fmaxf(aA[0] * inv + bv.x + bf2f((ushort_t)(zu.x & 0xFFFF)), 0.f);
                hv.y = fmaxf(aA[1] * inv + bv.y + bf2f((ushort_t)(zu.x >> 16)), 0.f);
                hv.z = fmaxf(aA[2] * inv + bv.z + bf2f((ushort_t)(zu.y & 0xFFFF)), 0.f);
                hv.w = fmaxf(aA[3] * inv + bv.w + bf2f((ushort_t)(zu.y >> 16)), 0.f);
                *reinterpret_cast<float4*>(&hld[nlA * 68 + 4 * fp]) = hv;
            }
            if (gB < N_NODES) {
                float inv = 1.f / fmaxf((float)ndeg[b * 64 + nlB], 1.f);
                uint2 zu = *reinterpret_cast<const uint2*>(&z1b[(size_t)gB * 64 + 4 * fp]);
                float4 hv;
                hv.x = fmaxf(aB[0] * inv + bv.x + bf2f((ushort_t)(zu.x & 0xFFFF)), 0.f);
                hv.y = fmaxf(aB[1] * inv + bv.y + bf2f((ushort_t)(zu.x >> 16)), 0.f);
                hv.z = fmaxf(aB[2] * inv + bv.z + bf2f((ushort_t)(zu.y & 0xFFFF)), 0.f);
                hv.w = fmaxf(aB[3] * inv + bv.w + bf2f((ushort_t)(zu.y >> 16)), 0.f);
                *reinterpret_cast<float4*>(&hld[nlB * 68 + 4 * fp]) = hv;
            }
        }
    }

    {
        int flat = (t & 255) * 8;
        int o = (flat >> 6) + ((t < 256) ? 0 : 32);
        int f = flat & 63;
        float* dstw = &wcat[o * 65 + f];
        dstw[0] = wp0.x; dstw[1] = wp0.y; dstw[2] = wp0.z; dstw[3] = wp0.w;
        dstw[4] = wp1.x; dstw[5] = wp1.y; dstw[6] = wp1.z; dstw[7] = wp1.w;
    }
    __syncthreads();

#pragma unroll
    for (int kp = 0; kp < 4; ++kp) {
        int nlA = w + 8 * (2 * kp), nlB = nlA + 8;
        float sA = 0.f, sB = 0.f;
        const float* wrow = &wcat[lane * 65];
#pragma unroll 8
        for (int f = 0; f < 64; ++f) {
            float wv = wrow[f];
            sA += hld[nlA * 68 + f] * wv;
            sB += hld[nlB * 68 + f] * wv;
        }
        int gA = nodeBase + nlA, gB = nodeBase + nlB;
        int o = lane & 31;
        if (gA < N_NODES) {
            if (lane < 32) y2b[(size_t)gA * 32 + o] = f2bf(sA);
            else           z2b[(size_t)gA * 32 + o] = f2bf(sA);
        }
        if (gB < N_NODES) {
            if (lane < 32) y2b[(size_t)gB * 32 + o] = f2bf(sB);
            else           z2b[(size_t)gB * 32 + o] = f2bf(sB);
        }
    }
}

// ---------------------------------------------------------------------------
// Layer-2 aggregate (unchanged r11): full bucket/block, dual-run gather.
// out = mean + bl2 + z2 (f32, float4 stores).
// ---------------------------------------------------------------------------
__global__ __launch_bounds__(512) void agg_layer2(const ushort_t* __restrict__ y2b,
                                                  const ushort_t* __restrict__ z2b,
                                                  const float* __restrict__ bl2,
                                                  const int* __restrict__ nstart,
                                                  const int* __restrict__ ndeg,
                                                  const ushort_t* __restrict__ esrc,
                                                  float* __restrict__ out) {
    __shared__ ushort_t esrcS[CAP2];
    int t = threadIdx.x, b = blockIdx.x;
    int lane = t & 63, w = t >> 6;
    int eo = lane >> 3, fp = lane & 7;

    float4 bv = *reinterpret_cast<const float4*>(&bl2[4 * fp]);

    const int nb = b * 65;
    int tot = nstart[nb + 64];
    for (int i = t; i < tot; i += 512) esrcS[i] = esrc[(size_t)b * CAP2 + i];
    __syncthreads();

    int nodeBase = b * BNODES;
#pragma unroll
    for (int kp = 0; kp < 4; ++kp) {
        int nlA = w + 8 * (2 * kp), nlB = w + 8 * (2 * kp + 1);
        int jA = nstart[nb + nlA], reA = nstart[nb + nlA + 1];
        int jB = nstart[nb + nlB], reB = nstart[nb + nlB + 1];
        float aA[4] = {0.f, 0.f, 0.f, 0.f};
        float aB[4] = {0.f, 0.f, 0.f, 0.f};

        while (jA + 15 < reA && jB + 15 < reB) {
            unsigned sA0 = esrcS[jA + eo], sA1 = esrcS[jA + 8 + eo];
            unsigned sB0 = esrcS[jB + eo], sB1 = esrcS[jB + 8 + eo];
            uint2 vA0 = *reinterpret_cast<const uint2*>(&y2b[(size_t)sA0 * 32 + 4 * fp]);
            uint2 vA1 = *reinterpret_cast<const uint2*>(&y2b[(size_t)sA1 * 32 + 4 * fp]);
            uint2 vB0 = *reinterpret_cast<const uint2*>(&y2b[(size_t)sB0 * 32 + 4 * fp]);
            uint2 vB1 = *reinterpret_cast<const uint2*>(&y2b[(size_t)sB1 * 32 + 4 * fp]);
            CVT2(vA0, aA) CVT2(vA1, aA) CVT2(vB0, aB) CVT2(vB1, aB)
            jA += 16; jB += 16;
        }
        while (jA + 15 < reA) {
            unsigned s0 = esrcS[jA + eo], s1 = esrcS[jA + 8 + eo];
            uint2 v0 = *reinterpret_cast<const uint2*>(&y2b[(size_t)s0 * 32 + 4 * fp]);
            uint2 v1 = *reinterpret_cast<const uint2*>(&y2b[(size_t)s1 * 32 + 4 * fp]);
            CVT2(v0, aA) CVT2(v1, aA)
            jA += 16;
        }
        if (jA < reA) {
            unsigned s0 = esrcS[jA + eo];
            uint2 v0 = *reinterpret_cast<const uint2*>(&y2b[(size_t)s0 * 32 + 4 * fp]);
            CVT2(v0, aA)
        }
        while (jB + 15 < reB) {
            unsigned s0 = esrcS[jB + eo], s1 = esrcS[jB + 8 + eo];
            uint2 v0 = *reinterpret_cast<const uint2*>(&y2b[(size_t)s0 * 32 + 4 * fp]);
            uint2 v1 = *reinterpret_cast<const uint2*>(&y2b[(size_t)s1 * 32 + 4 * fp]);
            CVT2(v0, aB) CVT2(v1, aB)
            jB += 16;
        }
        if (jB < reB) {
            unsigned s0 = esrcS[jB + eo];
            uint2 v0 = *reinterpret_cast<const uint2*>(&y2b[(size_t)s0 * 32 + 4 * fp]);
            CVT2(v0, aB)
        }

#pragma unroll
        for (int i = 0; i < 4; ++i) {
            aA[i] += __shfl_xor(aA[i], 8, 64);
            aA[i] += __shfl_xor(aA[i], 16, 64);
            aA[i] += __shfl_xor(aA[i], 32, 64);
            aB[i] += __shfl_xor(aB[i], 8, 64);
            aB[i] += __shfl_xor(aB[i], 16, 64);
            aB[i] += __shfl_xor(aB[i], 32, 64);
        }
        if (eo == 0) {
            int gA = nodeBase + nlA, gB = nodeBase + nlB;
            if (gA < N_NODES) {
                float inv = 1.f / fmaxf((float)ndeg[b * 64 + nlA], 1.f);
                uint2 zu = *reinterpret_cast<const uint2*>(&z2b[(size_t)gA * 32 + 4 * fp]);
                float4 ov;
                ov.x = aA[0] * inv + bv.x + bf2f((ushort_t)(zu.x & 0xFFFF));
                ov.y = aA[1] * inv + bv.y + bf2f((ushort_t)(zu.x >> 16));
                ov.z = aA[2] * inv + bv.z + bf2f((ushort_t)(zu.y & 0xFFFF));
                ov.w = aA[3] * inv + bv.w + bf2f((ushort_t)(zu.y >> 16));
                *reinterpret_cast<float4*>(&out[(size_t)gA * 32 + 4 * fp]) = ov;
            }
            if (gB < N_NODES) {
                float inv = 1.f / fmaxf((float)ndeg[b * 64 + nlB], 1.f);
                uint2 zu = *reinterpret_cast<const uint2*>(&z2b[(size_t)gB * 32 + 4 * fp]);
                float4 ov;
                ov.x = aB[0] * inv + bv.x + bf2f((ushort_t)(zu.x & 0xFFFF));
                ov.y = aB[1] * inv + bv.y + bf2f((ushort_t)(zu.x >> 16));
                ov.z = aB[2] * inv + bv.z + bf2f((ushort_t)(zu.y & 0xFFFF));
                ov.w = aB[3] * inv + bv.w + bf2f((ushort_t)(zu.y >> 16));
                *reinterpret_cast<float4*>(&out[(size_t)gB * 32 + 4 * fp]) = ov;
            }
        }
    }
}

extern "C" void kernel_launch(void* const* d_in, const int* in_sizes, int n_in,
                              void* d_out, int out_size, void* d_ws, size_t ws_size,
                              hipStream_t stream) {
    const float* x   = (const float*)d_in[0];
    const int*   ei  = (const int*)d_in[1];   // (2, N_EDGES) int32
    const float* Wl1 = (const float*)d_in[2];
    const float* bl1 = (const float*)d_in[3];
    const float* Wr1 = (const float*)d_in[4];
    const float* Wl2 = (const float*)d_in[5];
    const float* bl2 = (const float*)d_in[6];
    const float* Wr2 = (const float*)d_in[7];
    float* out = (float*)d_out;

    const int* src = ei;
    const int* dst = ei + N_EDGES;

    // Workspace layout (byte offsets, 16B-aligned). Total ~32.4 MB.
    // y1b/y2b carry an extra zero row at index 50000 (gather-pad target),
    // written by scatter_mm's mm-block 0.
    char* wsb = (char*)d_ws;
    int*      cursor = (int*)(wsb + 0);              //  4 KB (zeroed)
    unsigned* ebuf   = (unsigned*)(wsb + 4096);      //  782*2560*4 = 8,007,680
    ushort_t* esrc   = (ushort_t*)(wsb + 8011776);   //  782*3072*2 = 4,804,608
    int*      nstart = (int*)(wsb + 12816384);       //  782*65*4   =   203,320
    int*      ndeg   = (int*)(wsb + 13019712);       //  782*64*4   =   200,192
    ushort_t* y1b    = (ushort_t*)(wsb + 13219904);  //  50001*64*2 = 6,400,128
    ushort_t* z1b    = (ushort_t*)(wsb + 19620032);  //  50000*64*2 = 6,400,000
    ushort_t* y2b    = (ushort_t*)(wsb + 26020032);  //  50001*32*2 = 3,200,064
    ushort_t* z2b    = (ushort_t*)(wsb + 29220096);  //  50000*32*2 = 3,200,000

    hipMemsetAsync(cursor, 0, NBUCK * sizeof(int), stream);

    scatter_mm<<<SC_NBLK + MM_NBLK, 1024, 0, stream>>>(src, dst, cursor, ebuf,
                                                       x, Wl1, Wr1, y1b, z1b, y2b);
    refine_sort<<<NB_USED, 256, 0, stream>>>(cursor, ebuf, esrc, nstart, ndeg);
    agg_layer1<<<NB_USED, 512, 0, stream>>>(y1b, z1b, bl1, Wl2, Wr2, nstart, ndeg, esrc, y2b, z2b);
    agg_layer2<<<NB_USED, 512, 0, stream>>>(y2b, z2b, bl2, nstart, ndeg, esrc, out);
}